// Round 1
// baseline (1272.817 us; speedup 1.0000x reference)
//
#include <hip/hip_runtime.h>
#include <hip/hip_bf16.h>
#include <float.h>
#include <math.h>

#define Bn   16
#define Nn   8192
#define Cn   256
#define Hn   8
#define DHn  32
#define Mn   32      // N_HASHES * N_BUCKETS
#define DFFn 1024
#define TOK  64      // tokens per ln1 block

typedef __attribute__((ext_vector_type(8))) short short8;
typedef __attribute__((ext_vector_type(4))) float f32x4;

__device__ __forceinline__ float bf2f(ushort u) {
    union { unsigned int i; float f; } v; v.i = ((unsigned int)u) << 16; return v.f;
}
__device__ __forceinline__ ushort f2bf(float f) {
    union { float f; unsigned int i; } v; v.f = f;
    unsigned int r = (v.i + 0x7fffu + ((v.i >> 16) & 1u)) >> 16;
    return (ushort)r;
}

// ---------------------------------------------------------------------------
// K1: LN1 + LSH rotation/argmax + ATOMIC-FREE bucket pooling (scatter->gather)
// ---------------------------------------------------------------------------
__global__ __launch_bounds__(256, 4) void ln1_pool_kernel(
    const float* __restrict__ x, const float* __restrict__ rot,
    const float* __restrict__ g1, const float* __restrict__ b1,
    ushort* __restrict__ xbf, float* __restrict__ pool_part, float* __restrict__ cnt_part)
{
    __shared__ ushort xt[TOK][Cn];        // 32 KB bf16 x_hat tile
    __shared__ unsigned int idsS[TOK];    // packed 4x8bit bucket ids

    const int tid  = threadIdx.x;
    const int w    = tid >> 6, lane = tid & 63;
    const int o    = lane & 15;           // rotation output index (h*4+i)
    const int g    = lane >> 4;           // feature-chunk group
    const int fbase = g << 6;             // 64-feature chunk for dot

    float rwv[64];
    #pragma unroll
    for (int f = 0; f < 64; ++f) rwv[f] = rot[(fbase + f) * 16 + o];

    const int b  = blockIdx.x >> 7;           // 128 blocks per batch
    const int n0 = (blockIdx.x & 127) << 6;   // 64 tokens per block

    const float4 gv = *(const float4*)&g1[lane * 4];
    const float4 bv = *(const float4*)&b1[lane * 4];

    for (int it = 0; it < TOK / 4; ++it) {
        const int tloc = (it << 2) + w;
        const size_t roff = ((size_t)b * Nn + n0 + tloc) * Cn;
        float4 xv = *(const float4*)&x[roff + lane * 4];
        float s  = xv.x + xv.y + xv.z + xv.w;
        float s2 = xv.x * xv.x + xv.y * xv.y + xv.z * xv.z + xv.w * xv.w;
        #pragma unroll
        for (int msk = 1; msk < 64; msk <<= 1) { s += __shfl_xor(s, msk); s2 += __shfl_xor(s2, msk); }
        float mean = s * (1.f / Cn);
        float var  = s2 * (1.f / Cn) - mean * mean;
        float rr   = rsqrtf(var + 1e-5f);
        float xn[4];
        xn[0] = (xv.x - mean) * rr * gv.x + bv.x;
        xn[1] = (xv.y - mean) * rr * gv.y + bv.y;
        xn[2] = (xv.z - mean) * rr * gv.z + bv.z;
        xn[3] = (xv.w - mean) * rr * gv.w + bv.w;
        ushort4 ub; ub.x = f2bf(xn[0]); ub.y = f2bf(xn[1]); ub.z = f2bf(xn[2]); ub.w = f2bf(xn[3]);
        *(ushort4*)&xbf[roff + lane * 4] = ub;
        *(ushort4*)&xt[tloc][lane * 4] = ub;

        float d = 0.f;
        #pragma unroll
        for (int j = 0; j < 8; ++j) {
            short8 xs = *(const short8*)&xt[tloc][fbase + j * 8];
            #pragma unroll
            for (int u = 0; u < 8; ++u)
                d += bf2f((ushort)xs[u]) * rwv[j * 8 + u];
        }
        d += __shfl_xor(d, 16); d += __shfl_xor(d, 32);

        float d0 = __shfl(d, (lane & 12));
        float d1 = __shfl(d, (lane & 12) | 1);
        float d2 = __shfl(d, (lane & 12) | 2);
        float d3 = __shfl(d, (lane & 12) | 3);
        int bk = 0; float bb = d0;
        if (d1  > bb) { bb = d1;  bk = 1; }
        if (d2  > bb) { bb = d2;  bk = 2; }
        if (d3  > bb) { bb = d3;  bk = 3; }
        if (-d0 > bb) { bb = -d0; bk = 4; }
        if (-d1 > bb) { bb = -d1; bk = 5; }
        if (-d2 > bb) { bb = -d2; bk = 6; }
        if (-d3 > bb) { bb = -d3; bk = 7; }
        const unsigned int bk0 = __shfl(bk, 0), bk1 = __shfl(bk, 4),
                           bk2 = __shfl(bk, 8), bk3 = __shfl(bk, 12);
        if (lane == 0)
            idsS[tloc] = bk0 | (bk1 << 8) | (bk2 << 16) | (bk3 << 24);
    }
    __syncthreads();

    float pool[Mn];
    #pragma unroll
    for (int m = 0; m < Mn; ++m) pool[m] = 0.f;
    for (int t = 0; t < TOK; ++t) {
        const float xv = bf2f(xt[t][tid]);
        const unsigned int idw = idsS[t];
        #pragma unroll
        for (int h = 0; h < 4; ++h) {
            const unsigned int id = (idw >> (8 * h)) & 7u;
            #pragma unroll
            for (int mb = 0; mb < 8; ++mb)
                pool[h * 8 + mb] += (id == (unsigned int)mb) ? xv : 0.f;
        }
    }
    const size_t pbase = (size_t)blockIdx.x * (Mn * Cn);
    #pragma unroll
    for (int m = 0; m < Mn; ++m)
        pool_part[pbase + m * Cn + tid] = pool[m];

    if (tid < Mn) {
        const int h = tid >> 3, mb = tid & 7;
        float c = 0.f;
        for (int t = 0; t < TOK; ++t)
            c += (((idsS[t] >> (8 * h)) & 255u) == (unsigned int)mb) ? 1.f : 0.f;
        cnt_part[blockIdx.x * Mn + tid] = c;
    }
}

// ---------------------------------------------------------------------------
// K2: reduce partials -> rp_x -> k,v  (fp32). One block per (b, m).
// ---------------------------------------------------------------------------
__global__ __launch_bounds__(256) void kv_kernel(
    const float* __restrict__ pool_part, const float* __restrict__ cnt_part,
    const float* __restrict__ kv_w, float* __restrict__ kbuf, float* __restrict__ vbuf,
    float* __restrict__ countsF)
{
    __shared__ float rp[Cn];
    const int tid = threadIdx.x;
    const int b = blockIdx.x >> 5;
    const int m = blockIdx.x & 31;

    float acc = 0.f, cnt = 0.f;
    for (int j = 0; j < 128; ++j) {
        const int blk = b * 128 + j;
        acc += pool_part[(size_t)blk * (Mn * Cn) + m * Cn + tid];
        cnt += cnt_part[blk * Mn + m];
    }
    rp[tid] = acc / (cnt + 1e-20f);
    if (tid == 0) countsF[b * Mn + m] = cnt;
    __syncthreads();

    float a0 = 0.f, a1 = 0.f;
    for (int f = 0; f < Cn; ++f) {
        float rv = rp[f];
        a0 += rv * kv_w[f * 512 + tid];
        a1 += rv * kv_w[f * 512 + 256 + tid];
    }
    const int h = tid >> 5, d = tid & 31;
    kbuf[(((size_t)b * Hn + h) * Mn + m) * DHn + d] = a0;
    vbuf[(((size_t)b * Hn + h) * Mn + m) * DHn + d] = a1;
}

// ---------------------------------------------------------------------------
// K2b: fold q_w @ K^T * scale -> per-batch score weights WsT[b][h*32+m][f] (bf16)
// Replaces the q projection: S = x_hat @ Ws gives attention logits directly.
// ---------------------------------------------------------------------------
__global__ __launch_bounds__(256) void ws_build_kernel(
    const float* __restrict__ q_w, const float* __restrict__ kbuf, ushort* __restrict__ WsT)
{
    __shared__ float kSh[Mn * DHn];   // 4 KB, k for this (b,h)
    const int tid = threadIdx.x;
    const int b = blockIdx.x >> 3, h = blockIdx.x & 7;
    for (int i = tid; i < Mn * DHn; i += 256)
        kSh[i] = kbuf[((size_t)(b * Hn + h) * Mn) * DHn + i];
    __syncthreads();

    float qr[32];
    #pragma unroll
    for (int i = 0; i < 8; ++i) {
        float4 v = *(const float4*)&q_w[(size_t)tid * Cn + h * DHn + i * 4];
        qr[i*4+0] = v.x; qr[i*4+1] = v.y; qr[i*4+2] = v.z; qr[i*4+3] = v.w;
    }
    #pragma unroll 4
    for (int m = 0; m < Mn; ++m) {
        float s = 0.f;
        #pragma unroll
        for (int d = 0; d < DHn; ++d) s += qr[d] * kSh[m * DHn + d];
        // coalesced: all 256 threads write consecutive f for row j=h*32+m
        WsT[((size_t)b * Cn + h * Mn + m) * Cn + tid] = f2bf(s * 0.17677669529663687f);
    }
}

// ---------------------------------------------------------------------------
// GEMM: C[M][N] = A[M][K](bf16) x Bt[N][K](bf16)^T, 128x128 tile, BK=32
// bstride: per-batch offset (elements) into Bt (batch = row/8192); 0 = shared.
// ---------------------------------------------------------------------------
template<int EPI>
__global__ __launch_bounds__(256) void gemm_bt(
    const ushort* __restrict__ A, const ushort* __restrict__ Bt,
    const float* __restrict__ bias, const float* __restrict__ resid,
    void* __restrict__ Cp, int Mrows, int Ncols, int K, int bstride)
{
    __shared__ ushort As[128][40];
    __shared__ ushort Bs[128][40];
    const int tid  = threadIdx.x;
    const int lane = tid & 63;
    const int w    = tid >> 6;
    const int wm   = (w >> 1) << 6;
    const int wn   = (w & 1) << 6;
    const int lr   = lane & 15;
    const int lq   = lane >> 4;
    const int m0   = blockIdx.y << 7;
    const int n0   = blockIdx.x << 7;
    const int srow = tid >> 2;
    const int sch  = (tid & 3) << 3;
    const ushort* Btb = Bt + (size_t)(m0 >> 13) * (size_t)bstride;

    f32x4 acc[4][4];
    #pragma unroll
    for (int i = 0; i < 4; i++)
        #pragma unroll
        for (int j = 0; j < 4; j++)
            acc[i][j] = (f32x4){0.f, 0.f, 0.f, 0.f};

    for (int k0 = 0; k0 < K; k0 += 32) {
        *(uint4*)&As[srow][sch]      = *(const uint4*)&A[(size_t)(m0 + srow) * K + k0 + sch];
        *(uint4*)&As[srow + 64][sch] = *(const uint4*)&A[(size_t)(m0 + srow + 64) * K + k0 + sch];
        *(uint4*)&Bs[srow][sch]      = *(const uint4*)&Btb[(size_t)(n0 + srow) * K + k0 + sch];
        *(uint4*)&Bs[srow + 64][sch] = *(const uint4*)&Btb[(size_t)(n0 + srow + 64) * K + k0 + sch];
        __syncthreads();
        short8 af[4], bfr[4];
        #pragma unroll
        for (int i = 0; i < 4; i++) af[i]  = *(const short8*)&As[wm + i * 16 + lr][lq * 8];
        #pragma unroll
        for (int j = 0; j < 4; j++) bfr[j] = *(const short8*)&Bs[wn + j * 16 + lr][lq * 8];
        #pragma unroll
        for (int i = 0; i < 4; i++)
            #pragma unroll
            for (int j = 0; j < 4; j++)
                acc[i][j] = __builtin_amdgcn_mfma_f32_16x16x32_bf16(af[i], bfr[j], acc[i][j], 0, 0, 0);
        __syncthreads();
    }

    #pragma unroll
    for (int i = 0; i < 4; i++) {
        #pragma unroll
        for (int j = 0; j < 4; j++) {
            const int col = n0 + wn + j * 16 + lr;
            #pragma unroll
            for (int r = 0; r < 4; r++) {
                const int rw = m0 + wm + i * 16 + lq * 4 + r;
                float v = acc[i][j][r];
                if (EPI == 1) { v += bias[col]; v = 0.5f * v * (1.f + erff(v * 0.70710678118654752f)); }
                if (EPI == 2) {
                    v += bias[col] + resid[(size_t)rw * Ncols + col];
                    ((float*)Cp)[(size_t)rw * Ncols + col] = v;
                } else {
                    ((ushort*)Cp)[(size_t)rw * Ncols + col] = f2bf(v);
                }
            }
        }
    }
}

// ---------------------------------------------------------------------------
// K4 v2: softmax(S) @ V + residual + LayerNorm2, 8 lanes/token (1 per head),
// 2 tokens/lane (v-reads shared). Coalesced row IO; x2 kept in registers
// for LN2 (no global re-read). Only V staged in LDS (h-stride padded: the 8
// head-lanes hit disjoint bank groups -> conflict-free).
// ---------------------------------------------------------------------------
#define VSH 1028   // h-stride in floats: 1028 % 32 = 4 -> h*4 bank offset
#define GSH 36     // 36 % 32 = 4

__global__ __launch_bounds__(256) void attn2_ln2_kernel(
    const ushort* __restrict__ S, const float* __restrict__ vbuf,
    const float* __restrict__ counts, const float* __restrict__ x,
    const float* __restrict__ g2, const float* __restrict__ b2,
    float* __restrict__ x2, ushort* __restrict__ ybf)
{
    __shared__ float vS[Hn * VSH];            // ~32.1 KB
    __shared__ float gS[Hn * GSH], bS[Hn * GSH];
    __shared__ unsigned int mkS;
    const int tid = threadIdx.x;
    const int b = blockIdx.x >> 6;            // 64 blocks per batch
    const int nbase = (blockIdx.x & 63) << 7; // 128 tokens per block

    for (int i = tid; i < Hn * Mn * DHn; i += 256)
        vS[(i >> 10) * VSH + (i & 1023)] = vbuf[(size_t)b * (Hn * Mn * DHn) + i];
    gS[(tid >> 5) * GSH + (tid & 31)] = g2[tid];
    bS[(tid >> 5) * GSH + (tid & 31)] = b2[tid];
    if (tid == 0) {
        unsigned int mq = 0;
        for (int m = 0; m < Mn; ++m) if (counts[b * Mn + m] >= 1.f) mq |= (1u << m);
        mkS = mq;
    }
    __syncthreads();
    const unsigned int mk = mkS;
    const int w = tid >> 6, lane = tid & 63;
    const int t8 = lane >> 3, h = lane & 7;   // token's 8 head-lanes contiguous
    const float* vbase = &vS[h * VSH];
    const float* gp = &gS[h * GSH];
    const float* bp = &bS[h * GSH];

    for (int it = 0; it < 2; ++it) {
        const int nl = nbase + it * 64 + w * 16 + t8 * 2;
        const size_t offA = ((size_t)b * Nn + nl) * Cn + h * DHn;   // token A; B at +Cn

        // ---- load logits (bf16), masked softmax, fully in-register ----
        float pA[32], pB[32];
        #pragma unroll
        for (int i = 0; i < 4; ++i) {
            short8 sa = *(const short8*)&S[offA + i * 8];
            short8 sb = *(const short8*)&S[offA + Cn + i * 8];
            #pragma unroll
            for (int j = 0; j < 8; ++j) {
                pA[i * 8 + j] = bf2f((ushort)sa[j]);
                pB[i * 8 + j] = bf2f((ushort)sb[j]);
            }
        }
        float mxA = -FLT_MAX, mxB = -FLT_MAX;
        #pragma unroll
        for (int m = 0; m < 32; ++m) {
            if (!((mk >> m) & 1u)) { pA[m] = -FLT_MAX; pB[m] = -FLT_MAX; }
            mxA = fmaxf(mxA, pA[m]); mxB = fmaxf(mxB, pB[m]);
        }
        float dA = 0.f, dB = 0.f;
        #pragma unroll
        for (int m = 0; m < 32; ++m) {
            pA[m] = __expf(pA[m] - mxA); dA += pA[m];
            pB[m] = __expf(pB[m] - mxB); dB += pB[m];
        }
        const float iA = 1.f / dA, iB = 1.f / dB;

        // ---- PV: v read once, used for both tokens ----
        float oA[32], oB[32];
        #pragma unroll
        for (int i = 0; i < 32; ++i) { oA[i] = 0.f; oB[i] = 0.f; }
        #pragma unroll
        for (int m = 0; m < 32; ++m) {
            const float a = pA[m], c = pB[m];
            const float* vp = vbase + m * DHn;
            #pragma unroll
            for (int dq = 0; dq < 8; ++dq) {
                float4 v4 = *(const float4*)&vp[dq * 4];
                oA[dq*4+0] += a * v4.x; oA[dq*4+1] += a * v4.y;
                oA[dq*4+2] += a * v4.z; oA[dq*4+3] += a * v4.w;
                oB[dq*4+0] += c * v4.x; oB[dq*4+1] += c * v4.y;
                oB[dq*4+2] += c * v4.z; oB[dq*4+3] += c * v4.w;
            }
        }

        // ---- residual + x2 store (f32) + LN stats; keep r in registers ----
        float sA = 0.f, s2A = 0.f, sB = 0.f, s2B = 0.f;
        #pragma unroll
        for (int dq = 0; dq < 8; ++dq) {
            float4 xa = *(const float4*)&x[offA + dq * 4];
            float4 xb = *(const float4*)&x[offA + Cn + dq * 4];
            float r0 = xa.x + oA[dq*4+0] * iA;
            float r1 = xa.y + oA[dq*4+1] * iA;
            float r2 = xa.z + oA[dq*4+2] * iA;
            float r3 = xa.w + oA[dq*4+3] * iA;
            float u0 = xb.x + oB[dq*4+0] * iB;
            float u1 = xb.y + oB[dq*4+1] * iB;
            float u2 = xb.z + oB[dq*4+2] * iB;
            float u3 = xb.w + oB[dq*4+3] * iB;
            *(float4*)&x2[offA + dq * 4]      = make_float4(r0, r1, r2, r3);
            *(float4*)&x2[offA + Cn + dq * 4] = make_float4(u0, u1, u2, u3);
            oA[dq*4+0] = r0; oA[dq*4+1] = r1; oA[dq*4+2] = r2; oA[dq*4+3] = r3;
            oB[dq*4+0] = u0; oB[dq*4+1] = u1; oB[dq*4+2] = u2; oB[dq*4+3] = u3;
            sA += r0 + r1 + r2 + r3; s2A += r0*r0 + r1*r1 + r2*r2 + r3*r3;
            sB += u0 + u1 + u2 + u3; s2B += u0*u0 + u1*u1 + u2*u2 + u3*u3;
        }
        #pragma unroll
        for (int msk = 1; msk < 8; msk <<= 1) {
            sA += __shfl_xor(sA, msk);  s2A += __shfl_xor(s2A, msk);
            sB += __shfl_xor(sB, msk);  s2B += __shfl_xor(s2B, msk);
        }
        const float mA = sA * (1.f / Cn), vA = s2A * (1.f / Cn) - mA * mA;
        const float rrA = rsqrtf(vA + 1e-5f);
        const float mB = sB * (1.f / Cn), vB = s2B * (1.f / Cn) - mB * mB;
        const float rrB = rsqrtf(vB + 1e-5f);

        // ---- LN2 + bf16 store ----
        #pragma unroll
        for (int dq = 0; dq < 8; dq += 2) {
            short8 ya, yb;
            #pragma unroll
            for (int u = 0; u < 2; ++u) {
                float4 g4 = *(const float4*)&gp[(dq + u) * 4];
                float4 b4 = *(const float4*)&bp[(dq + u) * 4];
                ya[u*4+0] = (short)f2bf((oA[(dq+u)*4+0] - mA) * rrA * g4.x + b4.x);
                ya[u*4+1] = (short)f2bf((oA[(dq+u)*4+1] - mA) * rrA * g4.y + b4.y);
                ya[u*4+2] = (short)f2bf((oA[(dq+u)*4+2] - mA) * rrA * g4.z + b4.z);
                ya[u*4+3] = (short)f2bf((oA[(dq+u)*4+3] - mA) * rrA * g4.w + b4.w);
                yb[u*4+0] = (short)f2bf((oB[(dq+u)*4+0] - mB) * rrB * g4.x + b4.x);
                yb[u*4+1] = (short)f2bf((oB[(dq+u)*4+1] - mB) * rrB * g4.y + b4.y);
                yb[u*4+2] = (short)f2bf((oB[(dq+u)*4+2] - mB) * rrB * g4.z + b4.z);
                yb[u*4+3] = (short)f2bf((oB[(dq+u)*4+3] - mB) * rrB * g4.w + b4.w);
            }
            *(short8*)&ybf[offA + dq * 4]      = ya;
            *(short8*)&ybf[offA + Cn + dq * 4] = yb;
        }
    }
}

// ---------------------------------------------------------------------------
// Weight cast + transpose: W[R][Cc] f32 -> Wt[Cc][R] bf16
// ---------------------------------------------------------------------------
__global__ void wcast_kernel(const float* __restrict__ W, ushort* __restrict__ Wt, int R, int Cc)
{
    int idx = blockIdx.x * 256 + threadIdx.x;
    if (idx < R * Cc) {
        int r = idx / Cc, c = idx % Cc;
        Wt[(size_t)c * R + r] = f2bf(W[idx]);
    }
}

extern "C" void kernel_launch(void* const* d_in, const int* in_sizes, int n_in,
                              void* d_out, int out_size, void* d_ws, size_t ws_size,
                              hipStream_t stream)
{
    const float* x    = (const float*)d_in[0];
    const float* rot  = (const float*)d_in[1];
    const float* n1g  = (const float*)d_in[2];
    const float* n1b  = (const float*)d_in[3];
    const float* q_w  = (const float*)d_in[4];
    const float* kv_w = (const float*)d_in[5];
    const float* n2g  = (const float*)d_in[6];
    const float* n2b  = (const float*)d_in[7];
    const float* fc1w = (const float*)d_in[8];
    const float* fc1b = (const float*)d_in[9];
    const float* fc2w = (const float*)d_in[10];
    const float* fc2b = (const float*)d_in[11];

    char* ws = (char*)d_ws;
    // Workspace layout. h (268MB) aliases xbf+S (dead by fc1).
    // pool_part (67MB) and WsT (2MB) alias x2 region (both dead before attn writes x2).
    const size_t XBF_OFF = 0;                  // 67108864  bf16 x_ [131072][256]
    const size_t S_OFF   = 67108864ull;        // 67108864  bf16 attention logits S
    const size_t H_OFF   = 0;                  // 268435456 bf16 h (aliases above)
    const size_t X2_OFF  = 268435456ull;       // 134217728 f32 x2  (first 67MB: pool_part/WsT)
    const size_t PP_OFF  = X2_OFF;             // 67108864  f32 pool_part [2048][32][256]
    const size_t CP_OFF  = X2_OFF + 67108864;  // 262144    f32 cnt_part [2048][32]
    const size_t Y_OFF   = 402653184ull;       // 67108864  bf16 y
    const size_t CT_OFF  = 469762048ull;       // 2048      f32 countsF
    const size_t KB_OFF  = CT_OFF + 4096;      // 524288    f32 k [16][8][32][32]
    const size_t VB_OFF  = KB_OFF + 524288;    // 524288    f32 v
    const size_t F1T_OFF = VB_OFF + 524288;    // 524288    bf16 fc1^T
    const size_t F2T_OFF = F1T_OFF + 524288;   // 524288    bf16 fc2^T

    ushort* xbf    = (ushort*)(ws + XBF_OFF);
    ushort* Sbuf   = (ushort*)(ws + S_OFF);
    ushort* hbf    = (ushort*)(ws + H_OFF);
    float*  x2     = (float*)(ws + X2_OFF);
    float*  ppart  = (float*)(ws + PP_OFF);
    float*  cpart  = (float*)(ws + CP_OFF);
    ushort* WsT    = (ushort*)(ws + X2_OFF);   // 2MB, aliases pool_part (dead after kv)
    ushort* ybf    = (ushort*)(ws + Y_OFF);
    float*  countsF= (float*)(ws + CT_OFF);
    float*  kbuf   = (float*)(ws + KB_OFF);
    float*  vbuf   = (float*)(ws + VB_OFF);
    ushort* f1T    = (ushort*)(ws + F1T_OFF);
    ushort* f2T    = (ushort*)(ws + F2T_OFF);

    wcast_kernel<<<dim3(1024), 256, 0, stream>>>(fc1w, f1T, 256, 1024);
    wcast_kernel<<<dim3(1024), 256, 0, stream>>>(fc2w, f2T, 1024, 256);

    ln1_pool_kernel<<<dim3(Bn * 128), 256, 0, stream>>>(x, rot, n1g, n1b, xbf, ppart, cpart);
    kv_kernel<<<dim3(Bn * Mn), 256, 0, stream>>>(ppart, cpart, kv_w, kbuf, vbuf, countsF);
    ws_build_kernel<<<dim3(Bn * Hn), 256, 0, stream>>>(q_w, kbuf, WsT);
    // S = x_hat @ Ws_b : replaces the q projection (same GEMM shape, per-batch B)
    gemm_bt<0><<<dim3(2, 1024), 256, 0, stream>>>(xbf, WsT, nullptr, nullptr, Sbuf, Bn * Nn, Cn, Cn, Cn * Cn);
    attn2_ln2_kernel<<<dim3(Bn * 64), 256, 0, stream>>>(Sbuf, vbuf, countsF, x, n2g, n2b, x2, ybf);
    gemm_bt<1><<<dim3(8, 1024), 256, 0, stream>>>(ybf, f1T, fc1b, nullptr, hbf, Bn * Nn, DFFn, Cn, 0);
    gemm_bt<2><<<dim3(2, 1024), 256, 0, stream>>>(hbf, f2T, fc2b, x2, d_out, Bn * Nn, Cn, DFFn, 0);
}

// Round 3
// 939.370 us; speedup vs baseline: 1.3550x; 1.3550x over previous
//
#include <hip/hip_runtime.h>
#include <hip/hip_bf16.h>
#include <float.h>
#include <math.h>

#define Bn   16
#define Nn   8192
#define Cn   256
#define Hn   8
#define DHn  32
#define Mn   32      // N_HASHES * N_BUCKETS
#define DFFn 1024
#define TOK  64      // tokens per ln1 block

typedef __attribute__((ext_vector_type(8))) short short8;
typedef __attribute__((ext_vector_type(4))) float f32x4;

__device__ __forceinline__ float bf2f(ushort u) {
    union { unsigned int i; float f; } v; v.i = ((unsigned int)u) << 16; return v.f;
}
__device__ __forceinline__ ushort f2bf(float f) {
    union { float f; unsigned int i; } v; v.f = f;
    unsigned int r = (v.i + 0x7fffu + ((v.i >> 16) & 1u)) >> 16;
    return (ushort)r;
}

// ---------------------------------------------------------------------------
// K1: LN1 + LSH rotation/argmax + ATOMIC-FREE bucket pooling (scatter->gather)
// ---------------------------------------------------------------------------
__global__ __launch_bounds__(256, 4) void ln1_pool_kernel(
    const float* __restrict__ x, const float* __restrict__ rot,
    const float* __restrict__ g1, const float* __restrict__ b1,
    ushort* __restrict__ xbf, float* __restrict__ pool_part, float* __restrict__ cnt_part)
{
    __shared__ ushort xt[TOK][Cn];        // 32 KB bf16 x_hat tile
    __shared__ unsigned int idsS[TOK];    // packed 4x8bit bucket ids

    const int tid  = threadIdx.x;
    const int w    = tid >> 6, lane = tid & 63;
    const int o    = lane & 15;           // rotation output index (h*4+i)
    const int g    = lane >> 4;           // feature-chunk group
    const int fbase = g << 6;             // 64-feature chunk for dot

    float rwv[64];
    #pragma unroll
    for (int f = 0; f < 64; ++f) rwv[f] = rot[(fbase + f) * 16 + o];

    const int b  = blockIdx.x >> 7;           // 128 blocks per batch
    const int n0 = (blockIdx.x & 127) << 6;   // 64 tokens per block

    const float4 gv = *(const float4*)&g1[lane * 4];
    const float4 bv = *(const float4*)&b1[lane * 4];

    for (int it = 0; it < TOK / 4; ++it) {
        const int tloc = (it << 2) + w;
        const size_t roff = ((size_t)b * Nn + n0 + tloc) * Cn;
        float4 xv = *(const float4*)&x[roff + lane * 4];
        float s  = xv.x + xv.y + xv.z + xv.w;
        float s2 = xv.x * xv.x + xv.y * xv.y + xv.z * xv.z + xv.w * xv.w;
        #pragma unroll
        for (int msk = 1; msk < 64; msk <<= 1) { s += __shfl_xor(s, msk); s2 += __shfl_xor(s2, msk); }
        float mean = s * (1.f / Cn);
        float var  = s2 * (1.f / Cn) - mean * mean;
        float rr   = rsqrtf(var + 1e-5f);
        float xn[4];
        xn[0] = (xv.x - mean) * rr * gv.x + bv.x;
        xn[1] = (xv.y - mean) * rr * gv.y + bv.y;
        xn[2] = (xv.z - mean) * rr * gv.z + bv.z;
        xn[3] = (xv.w - mean) * rr * gv.w + bv.w;
        ushort4 ub; ub.x = f2bf(xn[0]); ub.y = f2bf(xn[1]); ub.z = f2bf(xn[2]); ub.w = f2bf(xn[3]);
        *(ushort4*)&xbf[roff + lane * 4] = ub;
        *(ushort4*)&xt[tloc][lane * 4] = ub;

        float d = 0.f;
        #pragma unroll
        for (int j = 0; j < 8; ++j) {
            short8 xs = *(const short8*)&xt[tloc][fbase + j * 8];
            #pragma unroll
            for (int u = 0; u < 8; ++u)
                d += bf2f((ushort)xs[u]) * rwv[j * 8 + u];
        }
        d += __shfl_xor(d, 16); d += __shfl_xor(d, 32);

        float d0 = __shfl(d, (lane & 12));
        float d1 = __shfl(d, (lane & 12) | 1);
        float d2 = __shfl(d, (lane & 12) | 2);
        float d3 = __shfl(d, (lane & 12) | 3);
        int bk = 0; float bb = d0;
        if (d1  > bb) { bb = d1;  bk = 1; }
        if (d2  > bb) { bb = d2;  bk = 2; }
        if (d3  > bb) { bb = d3;  bk = 3; }
        if (-d0 > bb) { bb = -d0; bk = 4; }
        if (-d1 > bb) { bb = -d1; bk = 5; }
        if (-d2 > bb) { bb = -d2; bk = 6; }
        if (-d3 > bb) { bb = -d3; bk = 7; }
        const unsigned int bk0 = __shfl(bk, 0), bk1 = __shfl(bk, 4),
                           bk2 = __shfl(bk, 8), bk3 = __shfl(bk, 12);
        if (lane == 0)
            idsS[tloc] = bk0 | (bk1 << 8) | (bk2 << 16) | (bk3 << 24);
    }
    __syncthreads();

    float pool[Mn];
    #pragma unroll
    for (int m = 0; m < Mn; ++m) pool[m] = 0.f;
    for (int t = 0; t < TOK; ++t) {
        const float xv = bf2f(xt[t][tid]);
        const unsigned int idw = idsS[t];
        #pragma unroll
        for (int h = 0; h < 4; ++h) {
            const unsigned int id = (idw >> (8 * h)) & 7u;
            #pragma unroll
            for (int mb = 0; mb < 8; ++mb)
                pool[h * 8 + mb] += (id == (unsigned int)mb) ? xv : 0.f;
        }
    }
    const size_t pbase = (size_t)blockIdx.x * (Mn * Cn);
    #pragma unroll
    for (int m = 0; m < Mn; ++m)
        pool_part[pbase + m * Cn + tid] = pool[m];

    if (tid < Mn) {
        const int h = tid >> 3, mb = tid & 7;
        float c = 0.f;
        for (int t = 0; t < TOK; ++t)
            c += (((idsS[t] >> (8 * h)) & 255u) == (unsigned int)mb) ? 1.f : 0.f;
        cnt_part[blockIdx.x * Mn + tid] = c;
    }
}

// ---------------------------------------------------------------------------
// K2: reduce partials -> rp_x -> k,v  (fp32). One block per (b, m).
// ---------------------------------------------------------------------------
__global__ __launch_bounds__(256) void kv_kernel(
    const float* __restrict__ pool_part, const float* __restrict__ cnt_part,
    const float* __restrict__ kv_w, float* __restrict__ kbuf, float* __restrict__ vbuf,
    float* __restrict__ countsF)
{
    __shared__ float rp[Cn];
    const int tid = threadIdx.x;
    const int b = blockIdx.x >> 5;
    const int m = blockIdx.x & 31;

    float acc = 0.f, cnt = 0.f;
    for (int j = 0; j < 128; ++j) {
        const int blk = b * 128 + j;
        acc += pool_part[(size_t)blk * (Mn * Cn) + m * Cn + tid];
        cnt += cnt_part[blk * Mn + m];
    }
    rp[tid] = acc / (cnt + 1e-20f);
    if (tid == 0) countsF[b * Mn + m] = cnt;
    __syncthreads();

    float a0 = 0.f, a1 = 0.f;
    for (int f = 0; f < Cn; ++f) {
        float rv = rp[f];
        a0 += rv * kv_w[f * 512 + tid];
        a1 += rv * kv_w[f * 512 + 256 + tid];
    }
    const int h = tid >> 5, d = tid & 31;
    kbuf[(((size_t)b * Hn + h) * Mn + m) * DHn + d] = a0;
    vbuf[(((size_t)b * Hn + h) * Mn + m) * DHn + d] = a1;
}

// ---------------------------------------------------------------------------
// K2b: fold q_w @ K^T * scale -> per-batch score weights WsT[b][h*32+m][f] (bf16)
// ---------------------------------------------------------------------------
__global__ __launch_bounds__(256) void ws_build_kernel(
    const float* __restrict__ q_w, const float* __restrict__ kbuf, ushort* __restrict__ WsT)
{
    __shared__ float kSh[Mn * DHn];   // 4 KB, k for this (b,h)
    const int tid = threadIdx.x;
    const int b = blockIdx.x >> 3, h = blockIdx.x & 7;
    for (int i = tid; i < Mn * DHn; i += 256)
        kSh[i] = kbuf[((size_t)(b * Hn + h) * Mn) * DHn + i];
    __syncthreads();

    float qr[32];
    #pragma unroll
    for (int i = 0; i < 8; ++i) {
        float4 v = *(const float4*)&q_w[(size_t)tid * Cn + h * DHn + i * 4];
        qr[i*4+0] = v.x; qr[i*4+1] = v.y; qr[i*4+2] = v.z; qr[i*4+3] = v.w;
    }
    #pragma unroll 4
    for (int m = 0; m < Mn; ++m) {
        float s = 0.f;
        #pragma unroll
        for (int d = 0; d < DHn; ++d) s += qr[d] * kSh[m * DHn + d];
        WsT[((size_t)b * Cn + h * Mn + m) * Cn + tid] = f2bf(s * 0.17677669529663687f);
    }
}

// ---------------------------------------------------------------------------
// GEMM: C[M][N] = A[M][K](bf16) x Bt[N][K](bf16)^T, 128x128 tile, BK=32
// bstride: per-batch offset (elements) into Bt (batch = row/8192); 0 = shared.
// ---------------------------------------------------------------------------
template<int EPI>
__global__ __launch_bounds__(256) void gemm_bt(
    const ushort* __restrict__ A, const ushort* __restrict__ Bt,
    const float* __restrict__ bias, const float* __restrict__ resid,
    void* __restrict__ Cp, int Mrows, int Ncols, int K, int bstride)
{
    __shared__ ushort As[128][40];
    __shared__ ushort Bs[128][40];
    const int tid  = threadIdx.x;
    const int lane = tid & 63;
    const int w    = tid >> 6;
    const int wm   = (w >> 1) << 6;
    const int wn   = (w & 1) << 6;
    const int lr   = lane & 15;
    const int lq   = lane >> 4;
    const int m0   = blockIdx.y << 7;
    const int n0   = blockIdx.x << 7;
    const int srow = tid >> 2;
    const int sch  = (tid & 3) << 3;
    const ushort* Btb = Bt + (size_t)(m0 >> 13) * (size_t)bstride;

    f32x4 acc[4][4];
    #pragma unroll
    for (int i = 0; i < 4; i++)
        #pragma unroll
        for (int j = 0; j < 4; j++)
            acc[i][j] = (f32x4){0.f, 0.f, 0.f, 0.f};

    for (int k0 = 0; k0 < K; k0 += 32) {
        *(uint4*)&As[srow][sch]      = *(const uint4*)&A[(size_t)(m0 + srow) * K + k0 + sch];
        *(uint4*)&As[srow + 64][sch] = *(const uint4*)&A[(size_t)(m0 + srow + 64) * K + k0 + sch];
        *(uint4*)&Bs[srow][sch]      = *(const uint4*)&Btb[(size_t)(n0 + srow) * K + k0 + sch];
        *(uint4*)&Bs[srow + 64][sch] = *(const uint4*)&Btb[(size_t)(n0 + srow + 64) * K + k0 + sch];
        __syncthreads();
        short8 af[4], bfr[4];
        #pragma unroll
        for (int i = 0; i < 4; i++) af[i]  = *(const short8*)&As[wm + i * 16 + lr][lq * 8];
        #pragma unroll
        for (int j = 0; j < 4; j++) bfr[j] = *(const short8*)&Bs[wn + j * 16 + lr][lq * 8];
        #pragma unroll
        for (int i = 0; i < 4; i++)
            #pragma unroll
            for (int j = 0; j < 4; j++)
                acc[i][j] = __builtin_amdgcn_mfma_f32_16x16x32_bf16(af[i], bfr[j], acc[i][j], 0, 0, 0);
        __syncthreads();
    }

    #pragma unroll
    for (int i = 0; i < 4; i++) {
        #pragma unroll
        for (int j = 0; j < 4; j++) {
            const int col = n0 + wn + j * 16 + lr;
            #pragma unroll
            for (int r = 0; r < 4; r++) {
                const int rw = m0 + wm + i * 16 + lq * 4 + r;
                float v = acc[i][j][r];
                if (EPI == 1) { v += bias[col]; v = 0.5f * v * (1.f + erff(v * 0.70710678118654752f)); }
                if (EPI == 2) {
                    v += bias[col] + resid[(size_t)rw * Ncols + col];
                    ((float*)Cp)[(size_t)rw * Ncols + col] = v;
                } else {
                    ((ushort*)Cp)[(size_t)rw * Ncols + col] = f2bf(v);
                }
            }
        }
    }
}

// ---------------------------------------------------------------------------
// K4 v3: softmax(S) @ V + residual + LN2. One head per THREAD (t=tid>>3,
// h=tid&7): p[32]+o[32] only -> ~120 VGPR, no spill. v in LDS, head stride
// 1028 floats (8 head addrs hit 8 distinct bank quads: conflict-free
// broadcast). Output tile staged in LDS, drained with perfectly coalesced
// float4/ushort4 stores (kills the write amplification seen in rounds 0-1).
// ---------------------------------------------------------------------------
#define VS3 1028     // 1028 % 32 == 4 -> head h offset = 4h banks
#define OB3 260      // outb row stride (floats)

__global__ __launch_bounds__(256) void attn3_ln2_kernel(
    const ushort* __restrict__ S, const float* __restrict__ vbuf,
    const float* __restrict__ counts, const float* __restrict__ x,
    const float* __restrict__ g2, const float* __restrict__ b2,
    float* __restrict__ x2, ushort* __restrict__ ybf)
{
    __shared__ float vS[Hn * VS3];        // 32.9 KB
    __shared__ float outb[32 * OB3];      // 33.3 KB  (x + attn, pre-LN)
    __shared__ float mS[32], rS[32];      // per-row mean, rsqrt(var)
    __shared__ unsigned int mkS;

    const int tid = threadIdx.x;
    const int b = blockIdx.x >> 8;            // 256 blocks per batch
    const int nbase = (blockIdx.x & 255) << 5; // 32 tokens per block

    for (int i = tid; i < Hn * Mn * DHn; i += 256)
        vS[(i >> 10) * VS3 + (i & 1023)] = vbuf[(size_t)b * (Hn * Mn * DHn) + i];
    {   // parallel mask build (wave 0)
        float cv = (tid < Mn) ? counts[b * Mn + tid] : 0.f;
        unsigned long long bal = __ballot(tid < Mn && cv >= 1.f);
        if (tid == 0) mkS = (unsigned int)bal;
    }
    __syncthreads();
    const unsigned int mk = mkS;

    const int t = tid >> 3;               // local token 0..31
    const int h = tid & 7;                // head
    const int n = nbase + t;
    const size_t off = ((size_t)b * Nn + n) * Cn + h * DHn;

    // ---- logits -> masked softmax (all in-thread, no shuffles) ----
    float p[32];
    #pragma unroll
    for (int u = 0; u < 4; ++u) {
        short8 sv = *(const short8*)&S[off + u * 8];
        #pragma unroll
        for (int j = 0; j < 8; ++j) p[u * 8 + j] = bf2f((ushort)sv[j]);
    }
    float mx = -FLT_MAX;
    #pragma unroll
    for (int m = 0; m < 32; ++m) {
        if (!((mk >> m) & 1u)) p[m] = -FLT_MAX;
        mx = fmaxf(mx, p[m]);
    }
    float den = 0.f;
    #pragma unroll
    for (int m = 0; m < 32; ++m) { p[m] = __expf(p[m] - mx); den += p[m]; }
    const float inv = 1.f / den;

    // ---- PV: broadcast LDS reads, conflict-free across the 8 head lanes ----
    float o[32];
    #pragma unroll
    for (int i = 0; i < 32; ++i) o[i] = 0.f;
    const float* vbase = &vS[h * VS3];
    #pragma unroll
    for (int m = 0; m < 32; ++m) {
        const float pm = p[m];
        const float* vp = vbase + m * DHn;
        #pragma unroll
        for (int dq = 0; dq < 8; ++dq) {
            float4 v4 = *(const float4*)&vp[dq * 4];
            o[dq*4+0] += pm * v4.x; o[dq*4+1] += pm * v4.y;
            o[dq*4+2] += pm * v4.z; o[dq*4+3] += pm * v4.w;
        }
    }

    // ---- residual; stash row tile in LDS; LN stats over 8 head lanes ----
    float s = 0.f, s2 = 0.f;
    #pragma unroll
    for (int dq = 0; dq < 8; ++dq) {
        float4 xv = *(const float4*)&x[off + dq * 4];
        float r0 = xv.x + o[dq*4+0] * inv;
        float r1 = xv.y + o[dq*4+1] * inv;
        float r2 = xv.z + o[dq*4+2] * inv;
        float r3 = xv.w + o[dq*4+3] * inv;
        *(float4*)&outb[t * OB3 + h * DHn + dq * 4] = make_float4(r0, r1, r2, r3);
        s  += r0 + r1 + r2 + r3;
        s2 += r0*r0 + r1*r1 + r2*r2 + r3*r3;
    }
    #pragma unroll
    for (int msk = 1; msk < 8; msk <<= 1) {
        s += __shfl_xor(s, msk); s2 += __shfl_xor(s2, msk);
    }
    if (h == 0) {
        const float mean = s * (1.f / Cn);
        const float var  = s2 * (1.f / Cn) - mean * mean;
        mS[t] = mean;
        rS[t] = rsqrtf(var + 1e-5f);
    }
    __syncthreads();

    // ---- drain: coalesced stores (wave covers 1KB contiguous per instr) ----
    const int lane = tid & 63;
    const float4 g4 = *(const float4*)&g2[lane * 4];
    const float4 b4 = *(const float4*)&b2[lane * 4];
    const size_t gbase = ((size_t)b * Nn + nbase) * Cn;
    #pragma unroll
    for (int j = 0; j < 8; ++j) {
        const int e   = j * 1024 + tid * 4;
        const int row = e >> 8;             // wave-uniform
        const int c   = e & 255;            // == lane*4
        float4 rv = *(const float4*)&outb[row * OB3 + c];
        *(float4*)&x2[gbase + e] = rv;
        const float mean = mS[row], rr = rS[row];
        ushort4 yb;
        yb.x = f2bf((rv.x - mean) * rr * g4.x + b4.x);
        yb.y = f2bf((rv.y - mean) * rr * g4.y + b4.y);
        yb.z = f2bf((rv.z - mean) * rr * g4.z + b4.z);
        yb.w = f2bf((rv.w - mean) * rr * g4.w + b4.w);
        *(ushort4*)&ybf[gbase + e] = yb;
    }
}

// ---------------------------------------------------------------------------
// Weight cast + transpose: W[R][Cc] f32 -> Wt[Cc][R] bf16
// ---------------------------------------------------------------------------
__global__ void wcast_kernel(const float* __restrict__ W, ushort* __restrict__ Wt, int R, int Cc)
{
    int idx = blockIdx.x * 256 + threadIdx.x;
    if (idx < R * Cc) {
        int r = idx / Cc, c = idx % Cc;
        Wt[(size_t)c * R + r] = f2bf(W[idx]);
    }
}

extern "C" void kernel_launch(void* const* d_in, const int* in_sizes, int n_in,
                              void* d_out, int out_size, void* d_ws, size_t ws_size,
                              hipStream_t stream)
{
    const float* x    = (const float*)d_in[0];
    const float* rot  = (const float*)d_in[1];
    const float* n1g  = (const float*)d_in[2];
    const float* n1b  = (const float*)d_in[3];
    const float* q_w  = (const float*)d_in[4];
    const float* kv_w = (const float*)d_in[5];
    const float* n2g  = (const float*)d_in[6];
    const float* n2b  = (const float*)d_in[7];
    const float* fc1w = (const float*)d_in[8];
    const float* fc1b = (const float*)d_in[9];
    const float* fc2w = (const float*)d_in[10];
    const float* fc2b = (const float*)d_in[11];

    char* ws = (char*)d_ws;
    const size_t XBF_OFF = 0;                  // 67108864  bf16 x_ [131072][256]
    const size_t S_OFF   = 67108864ull;        // 67108864  bf16 attention logits S
    const size_t H_OFF   = 0;                  // 268435456 bf16 h (aliases xbf+S, dead by fc1)
    const size_t X2_OFF  = 268435456ull;       // 134217728 f32 x2  (first 67MB: pool_part/WsT)
    const size_t PP_OFF  = X2_OFF;             // 67108864  f32 pool_part [2048][32][256]
    const size_t CP_OFF  = X2_OFF + 67108864;  // 262144    f32 cnt_part [2048][32]
    const size_t Y_OFF   = 402653184ull;       // 67108864  bf16 y
    const size_t CT_OFF  = 469762048ull;       // 2048      f32 countsF
    const size_t KB_OFF  = CT_OFF + 4096;      // 524288    f32 k [16][8][32][32]
    const size_t VB_OFF  = KB_OFF + 524288;    // 524288    f32 v
    const size_t F1T_OFF = VB_OFF + 524288;    // 524288    bf16 fc1^T
    const size_t F2T_OFF = F1T_OFF + 524288;   // 524288    bf16 fc2^T

    ushort* xbf    = (ushort*)(ws + XBF_OFF);
    ushort* Sbuf   = (ushort*)(ws + S_OFF);
    ushort* hbf    = (ushort*)(ws + H_OFF);
    float*  x2     = (float*)(ws + X2_OFF);
    float*  ppart  = (float*)(ws + PP_OFF);
    float*  cpart  = (float*)(ws + CP_OFF);
    ushort* WsT    = (ushort*)(ws + X2_OFF);   // 2MB, aliases pool_part (dead after kv)
    ushort* ybf    = (ushort*)(ws + Y_OFF);
    float*  countsF= (float*)(ws + CT_OFF);
    float*  kbuf   = (float*)(ws + KB_OFF);
    float*  vbuf   = (float*)(ws + VB_OFF);
    ushort* f1T    = (ushort*)(ws + F1T_OFF);
    ushort* f2T    = (ushort*)(ws + F2T_OFF);

    wcast_kernel<<<dim3(1024), 256, 0, stream>>>(fc1w, f1T, 256, 1024);
    wcast_kernel<<<dim3(1024), 256, 0, stream>>>(fc2w, f2T, 1024, 256);

    ln1_pool_kernel<<<dim3(Bn * 128), 256, 0, stream>>>(x, rot, n1g, n1b, xbf, ppart, cpart);
    kv_kernel<<<dim3(Bn * Mn), 256, 0, stream>>>(ppart, cpart, kv_w, kbuf, vbuf, countsF);
    ws_build_kernel<<<dim3(Bn * Hn), 256, 0, stream>>>(q_w, kbuf, WsT);
    // S = x_hat @ Ws_b : replaces the q projection (same GEMM shape, per-batch B)
    gemm_bt<0><<<dim3(2, 1024), 256, 0, stream>>>(xbf, WsT, nullptr, nullptr, Sbuf, Bn * Nn, Cn, Cn, Cn * Cn);
    attn3_ln2_kernel<<<dim3(Bn * 256), 256, 0, stream>>>(Sbuf, vbuf, countsF, x, n2g, n2b, x2, ybf);
    gemm_bt<1><<<dim3(8, 1024), 256, 0, stream>>>(ybf, f1T, fc1b, nullptr, hbf, Bn * Nn, DFFn, Cn, 0);
    gemm_bt<2><<<dim3(2, 1024), 256, 0, stream>>>(hbf, f2T, fc2b, x2, d_out, Bn * Nn, Cn, DFFn, 0);
}

// Round 4
// 910.942 us; speedup vs baseline: 1.3973x; 1.0312x over previous
//
#include <hip/hip_runtime.h>
#include <hip/hip_bf16.h>
#include <float.h>
#include <math.h>

#define Bn   16
#define Nn   8192
#define Cn   256
#define Hn   8
#define DHn  32
#define Mn   32      // N_HASHES * N_BUCKETS
#define DFFn 1024
#define TOK  64      // tokens per ln1 block

typedef __attribute__((ext_vector_type(8))) short short8;
typedef __attribute__((ext_vector_type(4))) float f32x4;

typedef const __attribute__((address_space(1))) unsigned int* gas_t;
typedef __attribute__((address_space(3))) unsigned int* las_t;

__device__ __forceinline__ float bf2f(ushort u) {
    union { unsigned int i; float f; } v; v.i = ((unsigned int)u) << 16; return v.f;
}
__device__ __forceinline__ ushort f2bf(float f) {
    union { float f; unsigned int i; } v; v.f = f;
    unsigned int r = (v.i + 0x7fffu + ((v.i >> 16) & 1u)) >> 16;
    return (ushort)r;
}

// Exact-GELU via Abramowitz-Stegun 7.1.26 erf (|eps| <= 1.5e-7):
// ~14 VALU ops vs ~100 for libm erff. Error 1e-7*|v| << bf16 rounding.
__device__ __forceinline__ float gelu_erf(float v) {
    const float z  = v * 0.70710678118654752f;
    const float az = fabsf(z);
    const float t  = __builtin_amdgcn_rcpf(1.f + 0.3275911f * az);
    float poly = t * (0.254829592f + t * (-0.284496736f +
                 t * (1.421413741f + t * (-1.453152027f + t * 1.061405429f))));
    const float e    = __expf(-az * az);
    const float erfa = 1.f - poly * e;          // erf(|z|)
    const float erfz = copysignf(erfa, z);
    return 0.5f * v * (1.f + erfz);
}

// ---------------------------------------------------------------------------
// K1: LN1 + LSH rotation/argmax + ATOMIC-FREE bucket pooling (scatter->gather)
// ---------------------------------------------------------------------------
__global__ __launch_bounds__(256, 4) void ln1_pool_kernel(
    const float* __restrict__ x, const float* __restrict__ rot,
    const float* __restrict__ g1, const float* __restrict__ b1,
    ushort* __restrict__ xbf, float* __restrict__ pool_part, float* __restrict__ cnt_part)
{
    __shared__ ushort xt[TOK][Cn];        // 32 KB bf16 x_hat tile
    __shared__ unsigned int idsS[TOK];    // packed 4x8bit bucket ids

    const int tid  = threadIdx.x;
    const int w    = tid >> 6, lane = tid & 63;
    const int o    = lane & 15;           // rotation output index (h*4+i)
    const int g    = lane >> 4;           // feature-chunk group
    const int fbase = g << 6;             // 64-feature chunk for dot

    float rwv[64];
    #pragma unroll
    for (int f = 0; f < 64; ++f) rwv[f] = rot[(fbase + f) * 16 + o];

    const int b  = blockIdx.x >> 7;           // 128 blocks per batch
    const int n0 = (blockIdx.x & 127) << 6;   // 64 tokens per block

    const float4 gv = *(const float4*)&g1[lane * 4];
    const float4 bv = *(const float4*)&b1[lane * 4];

    for (int it = 0; it < TOK / 4; ++it) {
        const int tloc = (it << 2) + w;
        const size_t roff = ((size_t)b * Nn + n0 + tloc) * Cn;
        float4 xv = *(const float4*)&x[roff + lane * 4];
        float s  = xv.x + xv.y + xv.z + xv.w;
        float s2 = xv.x * xv.x + xv.y * xv.y + xv.z * xv.z + xv.w * xv.w;
        #pragma unroll
        for (int msk = 1; msk < 64; msk <<= 1) { s += __shfl_xor(s, msk); s2 += __shfl_xor(s2, msk); }
        float mean = s * (1.f / Cn);
        float var  = s2 * (1.f / Cn) - mean * mean;
        float rr   = rsqrtf(var + 1e-5f);
        float xn[4];
        xn[0] = (xv.x - mean) * rr * gv.x + bv.x;
        xn[1] = (xv.y - mean) * rr * gv.y + bv.y;
        xn[2] = (xv.z - mean) * rr * gv.z + bv.z;
        xn[3] = (xv.w - mean) * rr * gv.w + bv.w;
        ushort4 ub; ub.x = f2bf(xn[0]); ub.y = f2bf(xn[1]); ub.z = f2bf(xn[2]); ub.w = f2bf(xn[3]);
        *(ushort4*)&xbf[roff + lane * 4] = ub;
        *(ushort4*)&xt[tloc][lane * 4] = ub;

        float d = 0.f;
        #pragma unroll
        for (int j = 0; j < 8; ++j) {
            short8 xs = *(const short8*)&xt[tloc][fbase + j * 8];
            #pragma unroll
            for (int u = 0; u < 8; ++u)
                d += bf2f((ushort)xs[u]) * rwv[j * 8 + u];
        }
        d += __shfl_xor(d, 16); d += __shfl_xor(d, 32);

        float d0 = __shfl(d, (lane & 12));
        float d1 = __shfl(d, (lane & 12) | 1);
        float d2 = __shfl(d, (lane & 12) | 2);
        float d3 = __shfl(d, (lane & 12) | 3);
        int bk = 0; float bb = d0;
        if (d1  > bb) { bb = d1;  bk = 1; }
        if (d2  > bb) { bb = d2;  bk = 2; }
        if (d3  > bb) { bb = d3;  bk = 3; }
        if (-d0 > bb) { bb = -d0; bk = 4; }
        if (-d1 > bb) { bb = -d1; bk = 5; }
        if (-d2 > bb) { bb = -d2; bk = 6; }
        if (-d3 > bb) { bb = -d3; bk = 7; }
        const unsigned int bk0 = __shfl(bk, 0), bk1 = __shfl(bk, 4),
                           bk2 = __shfl(bk, 8), bk3 = __shfl(bk, 12);
        if (lane == 0)
            idsS[tloc] = bk0 | (bk1 << 8) | (bk2 << 16) | (bk3 << 24);
    }
    __syncthreads();

    float pool[Mn];
    #pragma unroll
    for (int m = 0; m < Mn; ++m) pool[m] = 0.f;
    for (int t = 0; t < TOK; ++t) {
        const float xv = bf2f(xt[t][tid]);
        const unsigned int idw = idsS[t];
        #pragma unroll
        for (int h = 0; h < 4; ++h) {
            const unsigned int id = (idw >> (8 * h)) & 7u;
            #pragma unroll
            for (int mb = 0; mb < 8; ++mb)
                pool[h * 8 + mb] += (id == (unsigned int)mb) ? xv : 0.f;
        }
    }
    const size_t pbase = (size_t)blockIdx.x * (Mn * Cn);
    #pragma unroll
    for (int m = 0; m < Mn; ++m)
        pool_part[pbase + m * Cn + tid] = pool[m];

    if (tid < Mn) {
        const int h = tid >> 3, mb = tid & 7;
        float c = 0.f;
        for (int t = 0; t < TOK; ++t)
            c += (((idsS[t] >> (8 * h)) & 255u) == (unsigned int)mb) ? 1.f : 0.f;
        cnt_part[blockIdx.x * Mn + tid] = c;
    }
}

// ---------------------------------------------------------------------------
// K2: reduce partials -> rp_x -> k,v  (fp32). One block per (b, m).
// ---------------------------------------------------------------------------
__global__ __launch_bounds__(256) void kv_kernel(
    const float* __restrict__ pool_part, const float* __restrict__ cnt_part,
    const float* __restrict__ kv_w, float* __restrict__ kbuf, float* __restrict__ vbuf,
    float* __restrict__ countsF)
{
    __shared__ float rp[Cn];
    const int tid = threadIdx.x;
    const int b = blockIdx.x >> 5;
    const int m = blockIdx.x & 31;

    float acc = 0.f, cnt = 0.f;
    for (int j = 0; j < 128; ++j) {
        const int blk = b * 128 + j;
        acc += pool_part[(size_t)blk * (Mn * Cn) + m * Cn + tid];
        cnt += cnt_part[blk * Mn + m];
    }
    rp[tid] = acc / (cnt + 1e-20f);
    if (tid == 0) countsF[b * Mn + m] = cnt;
    __syncthreads();

    float a0 = 0.f, a1 = 0.f;
    for (int f = 0; f < Cn; ++f) {
        float rv = rp[f];
        a0 += rv * kv_w[f * 512 + tid];
        a1 += rv * kv_w[f * 512 + 256 + tid];
    }
    const int h = tid >> 5, d = tid & 31;
    kbuf[(((size_t)b * Hn + h) * Mn + m) * DHn + d] = a0;
    vbuf[(((size_t)b * Hn + h) * Mn + m) * DHn + d] = a1;
}

// ---------------------------------------------------------------------------
// K2b: fold q_w @ K^T * scale -> per-batch score weights WsT[b][h*32+m][f] (bf16)
// ---------------------------------------------------------------------------
__global__ __launch_bounds__(256) void ws_build_kernel(
    const float* __restrict__ q_w, const float* __restrict__ kbuf, ushort* __restrict__ WsT)
{
    __shared__ float kSh[Mn * DHn];   // 4 KB, k for this (b,h)
    const int tid = threadIdx.x;
    const int b = blockIdx.x >> 3, h = blockIdx.x & 7;
    for (int i = tid; i < Mn * DHn; i += 256)
        kSh[i] = kbuf[((size_t)(b * Hn + h) * Mn) * DHn + i];
    __syncthreads();

    float qr[32];
    #pragma unroll
    for (int i = 0; i < 8; ++i) {
        float4 v = *(const float4*)&q_w[(size_t)tid * Cn + h * DHn + i * 4];
        qr[i*4+0] = v.x; qr[i*4+1] = v.y; qr[i*4+2] = v.z; qr[i*4+3] = v.w;
    }
    #pragma unroll 4
    for (int m = 0; m < Mn; ++m) {
        float s = 0.f;
        #pragma unroll
        for (int d = 0; d < DHn; ++d) s += qr[d] * kSh[m * DHn + d];
        WsT[((size_t)b * Cn + h * Mn + m) * Cn + tid] = f2bf(s * 0.17677669529663687f);
    }
}

// ---------------------------------------------------------------------------
// GEMM: C[M][N] = A[M][K](bf16) x Bt[N][K](bf16)^T, 128x128 tile, BK=32.
// Staging via global_load_lds width=16 (m97 structure): linear [128][32] LDS,
// wave w stages 1KB chunks {w, w+4} of each tile (lane i -> row 16L+i/4,
// col (i&3)*8 -- matches HW's base+lane*16 linear write order).
// bstride: per-batch offset (elements) into Bt (batch = row/8192); 0 = shared.
// ---------------------------------------------------------------------------
template<int EPI>
__global__ __launch_bounds__(256) void gemm_bt(
    const ushort* __restrict__ A, const ushort* __restrict__ Bt,
    const float* __restrict__ bias, const float* __restrict__ resid,
    void* __restrict__ Cp, int Mrows, int Ncols, int K, int bstride)
{
    __shared__ ushort As[128 * 32];   // 8 KB, linear (required by global_load_lds)
    __shared__ ushort Bs[128 * 32];   // 8 KB
    const int tid  = threadIdx.x;
    const int lane = tid & 63;
    const int w    = tid >> 6;
    const int wm   = (w >> 1) << 6;
    const int wn   = (w & 1) << 6;
    const int lr   = lane & 15;
    const int lq   = lane >> 4;
    const int m0   = blockIdx.y << 7;
    const int n0   = blockIdx.x << 7;
    const ushort* Btb = Bt + (size_t)(m0 >> 13) * (size_t)bstride;

    // per-lane global sources for the 4 staging loads this wave owns
    const int srcRow = lane >> 2;          // 0..15
    const int srcCol = (lane & 3) << 3;    // 0,8,16,24 (ushorts, 16B units)
    const ushort* gA0 = &A  [(size_t)(m0 + w * 16      + srcRow) * K + srcCol];
    const ushort* gA1 = &A  [(size_t)(m0 + (w + 4) * 16 + srcRow) * K + srcCol];
    const ushort* gB0 = &Btb[(size_t)(n0 + w * 16      + srcRow) * K + srcCol];
    const ushort* gB1 = &Btb[(size_t)(n0 + (w + 4) * 16 + srcRow) * K + srcCol];
    ushort* lA0 = &As[ w      * 512];      // 16 rows x 32 ushorts = 1KB
    ushort* lA1 = &As[(w + 4) * 512];
    ushort* lB0 = &Bs[ w      * 512];
    ushort* lB1 = &Bs[(w + 4) * 512];

    f32x4 acc[4][4];
    #pragma unroll
    for (int i = 0; i < 4; i++)
        #pragma unroll
        for (int j = 0; j < 4; j++)
            acc[i][j] = (f32x4){0.f, 0.f, 0.f, 0.f};

    for (int k0 = 0; k0 < K; k0 += 32) {
        __builtin_amdgcn_global_load_lds((gas_t)(const void*)(gA0 + k0), (las_t)(void*)lA0, 16, 0, 0);
        __builtin_amdgcn_global_load_lds((gas_t)(const void*)(gA1 + k0), (las_t)(void*)lA1, 16, 0, 0);
        __builtin_amdgcn_global_load_lds((gas_t)(const void*)(gB0 + k0), (las_t)(void*)lB0, 16, 0, 0);
        __builtin_amdgcn_global_load_lds((gas_t)(const void*)(gB1 + k0), (las_t)(void*)lB1, 16, 0, 0);
        __syncthreads();   // compiler drains vmcnt(0) before s_barrier
        short8 af[4], bfr[4];
        #pragma unroll
        for (int i = 0; i < 4; i++) af[i]  = *(const short8*)&As[(wm + i * 16 + lr) * 32 + lq * 8];
        #pragma unroll
        for (int j = 0; j < 4; j++) bfr[j] = *(const short8*)&Bs[(wn + j * 16 + lr) * 32 + lq * 8];
        #pragma unroll
        for (int i = 0; i < 4; i++)
            #pragma unroll
            for (int j = 0; j < 4; j++)
                acc[i][j] = __builtin_amdgcn_mfma_f32_16x16x32_bf16(af[i], bfr[j], acc[i][j], 0, 0, 0);
        __syncthreads();
    }

    #pragma unroll
    for (int i = 0; i < 4; i++) {
        #pragma unroll
        for (int j = 0; j < 4; j++) {
            const int col = n0 + wn + j * 16 + lr;
            #pragma unroll
            for (int r = 0; r < 4; r++) {
                const int rw = m0 + wm + i * 16 + lq * 4 + r;
                float v = acc[i][j][r];
                if (EPI == 1) { v += bias[col]; v = gelu_erf(v); }
                if (EPI == 2) {
                    v += bias[col] + resid[(size_t)rw * Ncols + col];
                    ((float*)Cp)[(size_t)rw * Ncols + col] = v;
                } else {
                    ((ushort*)Cp)[(size_t)rw * Ncols + col] = f2bf(v);
                }
            }
        }
    }
}

// ---------------------------------------------------------------------------
// K4 v3: softmax(S) @ V + residual + LN2. One head per THREAD (t=tid>>3,
// h=tid&7). v in LDS head-stride 1028 (conflict-free broadcast). Output tile
// staged in LDS, drained with coalesced float4/ushort4 stores.
// ---------------------------------------------------------------------------
#define VS3 1028     // 1028 % 32 == 4 -> head h offset = 4h banks
#define OB3 260      // outb row stride (floats)

__global__ __launch_bounds__(256) void attn3_ln2_kernel(
    const ushort* __restrict__ S, const float* __restrict__ vbuf,
    const float* __restrict__ counts, const float* __restrict__ x,
    const float* __restrict__ g2, const float* __restrict__ b2,
    float* __restrict__ x2, ushort* __restrict__ ybf)
{
    __shared__ float vS[Hn * VS3];        // 32.9 KB
    __shared__ float outb[32 * OB3];      // 33.3 KB  (x + attn, pre-LN)
    __shared__ float mS[32], rS[32];      // per-row mean, rsqrt(var)
    __shared__ unsigned int mkS;

    const int tid = threadIdx.x;
    const int b = blockIdx.x >> 8;            // 256 blocks per batch
    const int nbase = (blockIdx.x & 255) << 5; // 32 tokens per block

    for (int i = tid; i < Hn * Mn * DHn; i += 256)
        vS[(i >> 10) * VS3 + (i & 1023)] = vbuf[(size_t)b * (Hn * Mn * DHn) + i];
    {   // parallel mask build (wave 0)
        float cv = (tid < Mn) ? counts[b * Mn + tid] : 0.f;
        unsigned long long bal = __ballot(tid < Mn && cv >= 1.f);
        if (tid == 0) mkS = (unsigned int)bal;
    }
    __syncthreads();
    const unsigned int mk = mkS;

    const int t = tid >> 3;               // local token 0..31
    const int h = tid & 7;                // head
    const int n = nbase + t;
    const size_t off = ((size_t)b * Nn + n) * Cn + h * DHn;

    // ---- logits -> masked softmax (all in-thread, no shuffles) ----
    float p[32];
    #pragma unroll
    for (int u = 0; u < 4; ++u) {
        short8 sv = *(const short8*)&S[off + u * 8];
        #pragma unroll
        for (int j = 0; j < 8; ++j) p[u * 8 + j] = bf2f((ushort)sv[j]);
    }
    float mx = -FLT_MAX;
    #pragma unroll
    for (int m = 0; m < 32; ++m) {
        if (!((mk >> m) & 1u)) p[m] = -FLT_MAX;
        mx = fmaxf(mx, p[m]);
    }
    float den = 0.f;
    #pragma unroll
    for (int m = 0; m < 32; ++m) { p[m] = __expf(p[m] - mx); den += p[m]; }
    const float inv = 1.f / den;

    // ---- PV: broadcast LDS reads, conflict-free across the 8 head lanes ----
    float o[32];
    #pragma unroll
    for (int i = 0; i < 32; ++i) o[i] = 0.f;
    const float* vbase = &vS[h * VS3];
    #pragma unroll
    for (int m = 0; m < 32; ++m) {
        const float pm = p[m];
        const float* vp = vbase + m * DHn;
        #pragma unroll
        for (int dq = 0; dq < 8; ++dq) {
            float4 v4 = *(const float4*)&vp[dq * 4];
            o[dq*4+0] += pm * v4.x; o[dq*4+1] += pm * v4.y;
            o[dq*4+2] += pm * v4.z; o[dq*4+3] += pm * v4.w;
        }
    }

    // ---- residual; stash row tile in LDS; LN stats over 8 head lanes ----
    float s = 0.f, s2 = 0.f;
    #pragma unroll
    for (int dq = 0; dq < 8; ++dq) {
        float4 xv = *(const float4*)&x[off + dq * 4];
        float r0 = xv.x + o[dq*4+0] * inv;
        float r1 = xv.y + o[dq*4+1] * inv;
        float r2 = xv.z + o[dq*4+2] * inv;
        float r3 = xv.w + o[dq*4+3] * inv;
        *(float4*)&outb[t * OB3 + h * DHn + dq * 4] = make_float4(r0, r1, r2, r3);
        s  += r0 + r1 + r2 + r3;
        s2 += r0*r0 + r1*r1 + r2*r2 + r3*r3;
    }
    #pragma unroll
    for (int msk = 1; msk < 8; msk <<= 1) {
        s += __shfl_xor(s, msk); s2 += __shfl_xor(s2, msk);
    }
    if (h == 0) {
        const float mean = s * (1.f / Cn);
        const float var  = s2 * (1.f / Cn) - mean * mean;
        mS[t] = mean;
        rS[t] = rsqrtf(var + 1e-5f);
    }
    __syncthreads();

    // ---- drain: coalesced stores (wave covers 1KB contiguous per instr) ----
    const int lane = tid & 63;
    const float4 g4 = *(const float4*)&g2[lane * 4];
    const float4 b4 = *(const float4*)&b2[lane * 4];
    const size_t gbase = ((size_t)b * Nn + nbase) * Cn;
    #pragma unroll
    for (int j = 0; j < 8; ++j) {
        const int e   = j * 1024 + tid * 4;
        const int row = e >> 8;             // wave-uniform
        const int c   = e & 255;            // == lane*4
        float4 rv = *(const float4*)&outb[row * OB3 + c];
        *(float4*)&x2[gbase + e] = rv;
        const float mean = mS[row], rr = rS[row];
        ushort4 yb;
        yb.x = f2bf((rv.x - mean) * rr * g4.x + b4.x);
        yb.y = f2bf((rv.y - mean) * rr * g4.y + b4.y);
        yb.z = f2bf((rv.z - mean) * rr * g4.z + b4.z);
        yb.w = f2bf((rv.w - mean) * rr * g4.w + b4.w);
        *(ushort4*)&ybf[gbase + e] = yb;
    }
}

// ---------------------------------------------------------------------------
// Weight cast + transpose: W[R][Cc] f32 -> Wt[Cc][R] bf16
// ---------------------------------------------------------------------------
__global__ void wcast_kernel(const float* __restrict__ W, ushort* __restrict__ Wt, int R, int Cc)
{
    int idx = blockIdx.x * 256 + threadIdx.x;
    if (idx < R * Cc) {
        int r = idx / Cc, c = idx % Cc;
        Wt[(size_t)c * R + r] = f2bf(W[idx]);
    }
}

extern "C" void kernel_launch(void* const* d_in, const int* in_sizes, int n_in,
                              void* d_out, int out_size, void* d_ws, size_t ws_size,
                              hipStream_t stream)
{
    const float* x    = (const float*)d_in[0];
    const float* rot  = (const float*)d_in[1];
    const float* n1g  = (const float*)d_in[2];
    const float* n1b  = (const float*)d_in[3];
    const float* q_w  = (const float*)d_in[4];
    const float* kv_w = (const float*)d_in[5];
    const float* n2g  = (const float*)d_in[6];
    const float* n2b  = (const float*)d_in[7];
    const float* fc1w = (const float*)d_in[8];
    const float* fc1b = (const float*)d_in[9];
    const float* fc2w = (const float*)d_in[10];
    const float* fc2b = (const float*)d_in[11];

    char* ws = (char*)d_ws;
    const size_t XBF_OFF = 0;                  // 67108864  bf16 x_ [131072][256]
    const size_t S_OFF   = 67108864ull;        // 67108864  bf16 attention logits S
    const size_t H_OFF   = 0;                  // 268435456 bf16 h (aliases xbf+S, dead by fc1)
    const size_t X2_OFF  = 268435456ull;       // 134217728 f32 x2  (first 67MB: pool_part/WsT)
    const size_t PP_OFF  = X2_OFF;             // 67108864  f32 pool_part [2048][32][256]
    const size_t CP_OFF  = X2_OFF + 67108864;  // 262144    f32 cnt_part [2048][32]
    const size_t Y_OFF   = 402653184ull;       // 67108864  bf16 y
    const size_t CT_OFF  = 469762048ull;       // 2048      f32 countsF
    const size_t KB_OFF  = CT_OFF + 4096;      // 524288    f32 k [16][8][32][32]
    const size_t VB_OFF  = KB_OFF + 524288;    // 524288    f32 v
    const size_t F1T_OFF = VB_OFF + 524288;    // 524288    bf16 fc1^T
    const size_t F2T_OFF = F1T_OFF + 524288;   // 524288    bf16 fc2^T

    ushort* xbf    = (ushort*)(ws + XBF_OFF);
    ushort* Sbuf   = (ushort*)(ws + S_OFF);
    ushort* hbf    = (ushort*)(ws + H_OFF);
    float*  x2     = (float*)(ws + X2_OFF);
    float*  ppart  = (float*)(ws + PP_OFF);
    float*  cpart  = (float*)(ws + CP_OFF);
    ushort* WsT    = (ushort*)(ws + X2_OFF);   // 2MB, aliases pool_part (dead after kv)
    ushort* ybf    = (ushort*)(ws + Y_OFF);
    float*  countsF= (float*)(ws + CT_OFF);
    float*  kbuf   = (float*)(ws + KB_OFF);
    float*  vbuf   = (float*)(ws + VB_OFF);
    ushort* f1T    = (ushort*)(ws + F1T_OFF);
    ushort* f2T    = (ushort*)(ws + F2T_OFF);

    wcast_kernel<<<dim3(1024), 256, 0, stream>>>(fc1w, f1T, 256, 1024);
    wcast_kernel<<<dim3(1024), 256, 0, stream>>>(fc2w, f2T, 1024, 256);

    ln1_pool_kernel<<<dim3(Bn * 128), 256, 0, stream>>>(x, rot, n1g, n1b, xbf, ppart, cpart);
    kv_kernel<<<dim3(Bn * Mn), 256, 0, stream>>>(ppart, cpart, kv_w, kbuf, vbuf, countsF);
    ws_build_kernel<<<dim3(Bn * Hn), 256, 0, stream>>>(q_w, kbuf, WsT);
    // S = x_hat @ Ws_b : replaces the q projection (same GEMM shape, per-batch B)
    gemm_bt<0><<<dim3(2, 1024), 256, 0, stream>>>(xbf, WsT, nullptr, nullptr, Sbuf, Bn * Nn, Cn, Cn, Cn * Cn);
    attn3_ln2_kernel<<<dim3(Bn * 256), 256, 0, stream>>>(Sbuf, vbuf, countsF, x, n2g, n2b, x2, ybf);
    gemm_bt<1><<<dim3(8, 1024), 256, 0, stream>>>(ybf, f1T, fc1b, nullptr, hbf, Bn * Nn, DFFn, Cn, 0);
    gemm_bt<2><<<dim3(2, 1024), 256, 0, stream>>>(hbf, f2T, fc2b, x2, d_out, Bn * Nn, Cn, DFFn, 0);
}

// Round 5
// 877.082 us; speedup vs baseline: 1.4512x; 1.0386x over previous
//
#include <hip/hip_runtime.h>
#include <hip/hip_bf16.h>
#include <float.h>
#include <math.h>

#define Bn   16
#define Nn   8192
#define Cn   256
#define Hn   8
#define DHn  32
#define Mn   32      // N_HASHES * N_BUCKETS
#define DFFn 1024
#define TOK  64      // tokens per ln1 block

typedef __attribute__((ext_vector_type(8))) short short8;
typedef __attribute__((ext_vector_type(4))) float f32x4;

typedef const __attribute__((address_space(1))) unsigned int* gas_t;
typedef __attribute__((address_space(3))) unsigned int* las_t;

__device__ __forceinline__ float bf2f(ushort u) {
    union { unsigned int i; float f; } v; v.i = ((unsigned int)u) << 16; return v.f;
}
__device__ __forceinline__ ushort f2bf(float f) {
    union { float f; unsigned int i; } v; v.f = f;
    unsigned int r = (v.i + 0x7fffu + ((v.i >> 16) & 1u)) >> 16;
    return (ushort)r;
}

// Exact-GELU via Abramowitz-Stegun 7.1.26 erf (|eps| <= 1.5e-7):
// ~14 VALU ops vs ~100 for libm erff. Error 1e-7*|v| << bf16 rounding.
__device__ __forceinline__ float gelu_erf(float v) {
    const float z  = v * 0.70710678118654752f;
    const float az = fabsf(z);
    const float t  = __builtin_amdgcn_rcpf(1.f + 0.3275911f * az);
    float poly = t * (0.254829592f + t * (-0.284496736f +
                 t * (1.421413741f + t * (-1.453152027f + t * 1.061405429f))));
    const float e    = __expf(-az * az);
    const float erfa = 1.f - poly * e;          // erf(|z|)
    const float erfz = copysignf(erfa, z);
    return 0.5f * v * (1.f + erfz);
}

// ---------------------------------------------------------------------------
// K1: LN1 + LSH rotation/argmax + ATOMIC-FREE bucket pooling (scatter->gather)
// ---------------------------------------------------------------------------
__global__ __launch_bounds__(256, 4) void ln1_pool_kernel(
    const float* __restrict__ x, const float* __restrict__ rot,
    const float* __restrict__ g1, const float* __restrict__ b1,
    ushort* __restrict__ xbf, float* __restrict__ pool_part, float* __restrict__ cnt_part)
{
    __shared__ ushort xt[TOK][Cn];        // 32 KB bf16 x_hat tile
    __shared__ unsigned int idsS[TOK];    // packed 4x8bit bucket ids

    const int tid  = threadIdx.x;
    const int w    = tid >> 6, lane = tid & 63;
    const int o    = lane & 15;           // rotation output index (h*4+i)
    const int g    = lane >> 4;           // feature-chunk group
    const int fbase = g << 6;             // 64-feature chunk for dot

    float rwv[64];
    #pragma unroll
    for (int f = 0; f < 64; ++f) rwv[f] = rot[(fbase + f) * 16 + o];

    const int b  = blockIdx.x >> 7;           // 128 blocks per batch
    const int n0 = (blockIdx.x & 127) << 6;   // 64 tokens per block

    const float4 gv = *(const float4*)&g1[lane * 4];
    const float4 bv = *(const float4*)&b1[lane * 4];

    for (int it = 0; it < TOK / 4; ++it) {
        const int tloc = (it << 2) + w;
        const size_t roff = ((size_t)b * Nn + n0 + tloc) * Cn;
        float4 xv = *(const float4*)&x[roff + lane * 4];
        float s  = xv.x + xv.y + xv.z + xv.w;
        float s2 = xv.x * xv.x + xv.y * xv.y + xv.z * xv.z + xv.w * xv.w;
        #pragma unroll
        for (int msk = 1; msk < 64; msk <<= 1) { s += __shfl_xor(s, msk); s2 += __shfl_xor(s2, msk); }
        float mean = s * (1.f / Cn);
        float var  = s2 * (1.f / Cn) - mean * mean;
        float rr   = rsqrtf(var + 1e-5f);
        float xn[4];
        xn[0] = (xv.x - mean) * rr * gv.x + bv.x;
        xn[1] = (xv.y - mean) * rr * gv.y + bv.y;
        xn[2] = (xv.z - mean) * rr * gv.z + bv.z;
        xn[3] = (xv.w - mean) * rr * gv.w + bv.w;
        ushort4 ub; ub.x = f2bf(xn[0]); ub.y = f2bf(xn[1]); ub.z = f2bf(xn[2]); ub.w = f2bf(xn[3]);
        *(ushort4*)&xbf[roff + lane * 4] = ub;
        *(ushort4*)&xt[tloc][lane * 4] = ub;

        float d = 0.f;
        #pragma unroll
        for (int j = 0; j < 8; ++j) {
            short8 xs = *(const short8*)&xt[tloc][fbase + j * 8];
            #pragma unroll
            for (int u = 0; u < 8; ++u)
                d += bf2f((ushort)xs[u]) * rwv[j * 8 + u];
        }
        d += __shfl_xor(d, 16); d += __shfl_xor(d, 32);

        float d0 = __shfl(d, (lane & 12));
        float d1 = __shfl(d, (lane & 12) | 1);
        float d2 = __shfl(d, (lane & 12) | 2);
        float d3 = __shfl(d, (lane & 12) | 3);
        int bk = 0; float bb = d0;
        if (d1  > bb) { bb = d1;  bk = 1; }
        if (d2  > bb) { bb = d2;  bk = 2; }
        if (d3  > bb) { bb = d3;  bk = 3; }
        if (-d0 > bb) { bb = -d0; bk = 4; }
        if (-d1 > bb) { bb = -d1; bk = 5; }
        if (-d2 > bb) { bb = -d2; bk = 6; }
        if (-d3 > bb) { bb = -d3; bk = 7; }
        const unsigned int bk0 = __shfl(bk, 0), bk1 = __shfl(bk, 4),
                           bk2 = __shfl(bk, 8), bk3 = __shfl(bk, 12);
        if (lane == 0)
            idsS[tloc] = bk0 | (bk1 << 8) | (bk2 << 16) | (bk3 << 24);
    }
    __syncthreads();

    float pool[Mn];
    #pragma unroll
    for (int m = 0; m < Mn; ++m) pool[m] = 0.f;
    for (int t = 0; t < TOK; ++t) {
        const float xv = bf2f(xt[t][tid]);
        const unsigned int idw = idsS[t];
        #pragma unroll
        for (int h = 0; h < 4; ++h) {
            const unsigned int id = (idw >> (8 * h)) & 7u;
            #pragma unroll
            for (int mb = 0; mb < 8; ++mb)
                pool[h * 8 + mb] += (id == (unsigned int)mb) ? xv : 0.f;
        }
    }
    const size_t pbase = (size_t)blockIdx.x * (Mn * Cn);
    #pragma unroll
    for (int m = 0; m < Mn; ++m)
        pool_part[pbase + m * Cn + tid] = pool[m];

    if (tid < Mn) {
        const int h = tid >> 3, mb = tid & 7;
        float c = 0.f;
        for (int t = 0; t < TOK; ++t)
            c += (((idsS[t] >> (8 * h)) & 255u) == (unsigned int)mb) ? 1.f : 0.f;
        cnt_part[blockIdx.x * Mn + tid] = c;
    }
}

// ---------------------------------------------------------------------------
// K2: reduce partials -> rp_x -> k,v  (fp32). One block per (b, m).
// ---------------------------------------------------------------------------
__global__ __launch_bounds__(256) void kv_kernel(
    const float* __restrict__ pool_part, const float* __restrict__ cnt_part,
    const float* __restrict__ kv_w, float* __restrict__ kbuf, float* __restrict__ vbuf,
    float* __restrict__ countsF)
{
    __shared__ float rp[Cn];
    const int tid = threadIdx.x;
    const int b = blockIdx.x >> 5;
    const int m = blockIdx.x & 31;

    float acc = 0.f, cnt = 0.f;
    for (int j = 0; j < 128; ++j) {
        const int blk = b * 128 + j;
        acc += pool_part[(size_t)blk * (Mn * Cn) + m * Cn + tid];
        cnt += cnt_part[blk * Mn + m];
    }
    rp[tid] = acc / (cnt + 1e-20f);
    if (tid == 0) countsF[b * Mn + m] = cnt;
    __syncthreads();

    float a0 = 0.f, a1 = 0.f;
    for (int f = 0; f < Cn; ++f) {
        float rv = rp[f];
        a0 += rv * kv_w[f * 512 + tid];
        a1 += rv * kv_w[f * 512 + 256 + tid];
    }
    const int h = tid >> 5, d = tid & 31;
    kbuf[(((size_t)b * Hn + h) * Mn + m) * DHn + d] = a0;
    vbuf[(((size_t)b * Hn + h) * Mn + m) * DHn + d] = a1;
}

// ---------------------------------------------------------------------------
// K2b: fold q_w @ K^T * scale -> per-batch score weights WsT[b][h*32+m][f] (bf16)
// ---------------------------------------------------------------------------
__global__ __launch_bounds__(256) void ws_build_kernel(
    const float* __restrict__ q_w, const float* __restrict__ kbuf, ushort* __restrict__ WsT)
{
    __shared__ float kSh[Mn * DHn];   // 4 KB, k for this (b,h)
    const int tid = threadIdx.x;
    const int b = blockIdx.x >> 3, h = blockIdx.x & 7;
    for (int i = tid; i < Mn * DHn; i += 256)
        kSh[i] = kbuf[((size_t)(b * Hn + h) * Mn) * DHn + i];
    __syncthreads();

    float qr[32];
    #pragma unroll
    for (int i = 0; i < 8; ++i) {
        float4 v = *(const float4*)&q_w[(size_t)tid * Cn + h * DHn + i * 4];
        qr[i*4+0] = v.x; qr[i*4+1] = v.y; qr[i*4+2] = v.z; qr[i*4+3] = v.w;
    }
    #pragma unroll 4
    for (int m = 0; m < Mn; ++m) {
        float s = 0.f;
        #pragma unroll
        for (int d = 0; d < DHn; ++d) s += qr[d] * kSh[m * DHn + d];
        WsT[((size_t)b * Cn + h * Mn + m) * Cn + tid] = f2bf(s * 0.17677669529663687f);
    }
}

// ---------------------------------------------------------------------------
// GEMM: C[M][N] = A[M][K](bf16) x Bt[N][K](bf16)^T, 128x128 tile, BK=32.
// T3-minimum 2-phase pipeline: double-buffered LDS, STAGE(t+1) issued before
// compute(t), ONE vmcnt(0)+barrier per K-step (load latency hides under MFMA).
// T1 XCD swizzle: blocks sharing an A-panel become consecutive on one XCD ->
// A-panel L2 reuse (kills the 4x A re-fetch seen in round 4).
// 1-D grid, gridDim.x % 8 == 0 required (2048/8192: ok).
// bstride: per-batch offset (elements) into Bt (batch = row/8192); 0 = shared.
// ---------------------------------------------------------------------------
template<int EPI>
__global__ __launch_bounds__(256) void gemm_bt(
    const ushort* __restrict__ A, const ushort* __restrict__ Bt,
    const float* __restrict__ bias, const float* __restrict__ resid,
    void* __restrict__ Cp, int Mrows, int Ncols, int K, int bstride)
{
    __shared__ ushort As[2][128 * 32];   // 2 x 8 KB, linear (global_load_lds dest)
    __shared__ ushort Bs[2][128 * 32];   // 2 x 8 KB
    const int tid  = threadIdx.x;
    const int lane = tid & 63;
    const int w    = tid >> 6;
    const int wm   = (w >> 1) << 6;
    const int wn   = (w & 1) << 6;
    const int lr   = lane & 15;
    const int lq   = lane >> 4;

    // XCD-grouping swizzle (bijective: gridDim.x % 8 == 0). XCD k (= id&7,
    // round-robin dispatch) gets the contiguous wg range [k*cpx, (k+1)*cpx):
    // the ntx n-tiles of each m-panel run consecutively on ONE XCD.
    const int id  = blockIdx.x;
    const int cpx = gridDim.x >> 3;
    const int wg  = (id & 7) * cpx + (id >> 3);
    const int ntx = Ncols >> 7;                // n-tiles: 2 or 8 (pow2)
    const int nts = __builtin_ctz(ntx);
    const int m0  = (wg >> nts) << 7;
    const int n0  = (wg & (ntx - 1)) << 7;

    const ushort* Btb = Bt + (size_t)(m0 >> 13) * (size_t)bstride;

    // per-lane global sources for the 4 staging loads this wave owns
    const int srcRow = lane >> 2;          // 0..15
    const int srcCol = (lane & 3) << 3;    // 0,8,16,24 ushorts (16B units)
    const ushort* gA0 = &A  [(size_t)(m0 + w * 16       + srcRow) * K + srcCol];
    const ushort* gA1 = &A  [(size_t)(m0 + (w + 4) * 16 + srcRow) * K + srcCol];
    const ushort* gB0 = &Btb[(size_t)(n0 + w * 16       + srcRow) * K + srcCol];
    const ushort* gB1 = &Btb[(size_t)(n0 + (w + 4) * 16 + srcRow) * K + srcCol];

    f32x4 acc[4][4];
    #pragma unroll
    for (int i = 0; i < 4; i++)
        #pragma unroll
        for (int j = 0; j < 4; j++)
            acc[i][j] = (f32x4){0.f, 0.f, 0.f, 0.f};

    const int nt = K >> 5;

    // prologue: stage tile 0 into buffer 0
    __builtin_amdgcn_global_load_lds((gas_t)(const void*)gA0, (las_t)(void*)&As[0][ w      * 512], 16, 0, 0);
    __builtin_amdgcn_global_load_lds((gas_t)(const void*)gA1, (las_t)(void*)&As[0][(w + 4) * 512], 16, 0, 0);
    __builtin_amdgcn_global_load_lds((gas_t)(const void*)gB0, (las_t)(void*)&Bs[0][ w      * 512], 16, 0, 0);
    __builtin_amdgcn_global_load_lds((gas_t)(const void*)gB1, (las_t)(void*)&Bs[0][(w + 4) * 512], 16, 0, 0);
    __syncthreads();   // vmcnt(0) drain + barrier

    int cur = 0;
    for (int t = 0; t < nt - 1; ++t) {
        const int k1 = (t + 1) << 5;
        const int nxt = cur ^ 1;
        // STAGE next tile first (latency hides under this tile's compute).
        // buf[nxt] was last READ at iter t-1, all waves past that barrier.
        __builtin_amdgcn_global_load_lds((gas_t)(const void*)(gA0 + k1), (las_t)(void*)&As[nxt][ w      * 512], 16, 0, 0);
        __builtin_amdgcn_global_load_lds((gas_t)(const void*)(gA1 + k1), (las_t)(void*)&As[nxt][(w + 4) * 512], 16, 0, 0);
        __builtin_amdgcn_global_load_lds((gas_t)(const void*)(gB0 + k1), (las_t)(void*)&Bs[nxt][ w      * 512], 16, 0, 0);
        __builtin_amdgcn_global_load_lds((gas_t)(const void*)(gB1 + k1), (las_t)(void*)&Bs[nxt][(w + 4) * 512], 16, 0, 0);
        // compute current tile
        short8 af[4], bfr[4];
        #pragma unroll
        for (int i = 0; i < 4; i++) af[i]  = *(const short8*)&As[cur][(wm + i * 16 + lr) * 32 + lq * 8];
        #pragma unroll
        for (int j = 0; j < 4; j++) bfr[j] = *(const short8*)&Bs[cur][(wn + j * 16 + lr) * 32 + lq * 8];
        #pragma unroll
        for (int i = 0; i < 4; i++)
            #pragma unroll
            for (int j = 0; j < 4; j++)
                acc[i][j] = __builtin_amdgcn_mfma_f32_16x16x32_bf16(af[i], bfr[j], acc[i][j], 0, 0, 0);
        __syncthreads();   // single vmcnt(0)+barrier per K-step
        cur = nxt;
    }
    {   // epilogue K-step: compute last tile, no prefetch
        short8 af[4], bfr[4];
        #pragma unroll
        for (int i = 0; i < 4; i++) af[i]  = *(const short8*)&As[cur][(wm + i * 16 + lr) * 32 + lq * 8];
        #pragma unroll
        for (int j = 0; j < 4; j++) bfr[j] = *(const short8*)&Bs[cur][(wn + j * 16 + lr) * 32 + lq * 8];
        #pragma unroll
        for (int i = 0; i < 4; i++)
            #pragma unroll
            for (int j = 0; j < 4; j++)
                acc[i][j] = __builtin_amdgcn_mfma_f32_16x16x32_bf16(af[i], bfr[j], acc[i][j], 0, 0, 0);
    }

    #pragma unroll
    for (int i = 0; i < 4; i++) {
        #pragma unroll
        for (int j = 0; j < 4; j++) {
            const int col = n0 + wn + j * 16 + lr;
            #pragma unroll
            for (int r = 0; r < 4; r++) {
                const int rw = m0 + wm + i * 16 + lq * 4 + r;
                float v = acc[i][j][r];
                if (EPI == 1) { v += bias[col]; v = gelu_erf(v); }
                if (EPI == 2) {
                    v += bias[col] + resid[(size_t)rw * Ncols + col];
                    ((float*)Cp)[(size_t)rw * Ncols + col] = v;
                } else {
                    ((ushort*)Cp)[(size_t)rw * Ncols + col] = f2bf(v);
                }
            }
        }
    }
}

// ---------------------------------------------------------------------------
// K4 v3: softmax(S) @ V + residual + LN2. One head per THREAD (t=tid>>3,
// h=tid&7). v in LDS head-stride 1028 (conflict-free broadcast). Output tile
// staged in LDS, drained with coalesced float4/ushort4 stores.
// ---------------------------------------------------------------------------
#define VS3 1028     // 1028 % 32 == 4 -> head h offset = 4h banks
#define OB3 260      // outb row stride (floats)

__global__ __launch_bounds__(256) void attn3_ln2_kernel(
    const ushort* __restrict__ S, const float* __restrict__ vbuf,
    const float* __restrict__ counts, const float* __restrict__ x,
    const float* __restrict__ g2, const float* __restrict__ b2,
    float* __restrict__ x2, ushort* __restrict__ ybf)
{
    __shared__ float vS[Hn * VS3];        // 32.9 KB
    __shared__ float outb[32 * OB3];      // 33.3 KB  (x + attn, pre-LN)
    __shared__ float mS[32], rS[32];      // per-row mean, rsqrt(var)
    __shared__ unsigned int mkS;

    const int tid = threadIdx.x;
    const int b = blockIdx.x >> 8;            // 256 blocks per batch
    const int nbase = (blockIdx.x & 255) << 5; // 32 tokens per block

    for (int i = tid; i < Hn * Mn * DHn; i += 256)
        vS[(i >> 10) * VS3 + (i & 1023)] = vbuf[(size_t)b * (Hn * Mn * DHn) + i];
    {   // parallel mask build (wave 0)
        float cv = (tid < Mn) ? counts[b * Mn + tid] : 0.f;
        unsigned long long bal = __ballot(tid < Mn && cv >= 1.f);
        if (tid == 0) mkS = (unsigned int)bal;
    }
    __syncthreads();
    const unsigned int mk = mkS;

    const int t = tid >> 3;               // local token 0..31
    const int h = tid & 7;                // head
    const int n = nbase + t;
    const size_t off = ((size_t)b * Nn + n) * Cn + h * DHn;

    // ---- logits -> masked softmax (all in-thread, no shuffles) ----
    float p[32];
    #pragma unroll
    for (int u = 0; u < 4; ++u) {
        short8 sv = *(const short8*)&S[off + u * 8];
        #pragma unroll
        for (int j = 0; j < 8; ++j) p[u * 8 + j] = bf2f((ushort)sv[j]);
    }
    float mx = -FLT_MAX;
    #pragma unroll
    for (int m = 0; m < 32; ++m) {
        if (!((mk >> m) & 1u)) p[m] = -FLT_MAX;
        mx = fmaxf(mx, p[m]);
    }
    float den = 0.f;
    #pragma unroll
    for (int m = 0; m < 32; ++m) { p[m] = __expf(p[m] - mx); den += p[m]; }
    const float inv = 1.f / den;

    // ---- PV: broadcast LDS reads, conflict-free across the 8 head lanes ----
    float o[32];
    #pragma unroll
    for (int i = 0; i < 32; ++i) o[i] = 0.f;
    const float* vbase = &vS[h * VS3];
    #pragma unroll
    for (int m = 0; m < 32; ++m) {
        const float pm = p[m];
        const float* vp = vbase + m * DHn;
        #pragma unroll
        for (int dq = 0; dq < 8; ++dq) {
            float4 v4 = *(const float4*)&vp[dq * 4];
            o[dq*4+0] += pm * v4.x; o[dq*4+1] += pm * v4.y;
            o[dq*4+2] += pm * v4.z; o[dq*4+3] += pm * v4.w;
        }
    }

    // ---- residual; stash row tile in LDS; LN stats over 8 head lanes ----
    float s = 0.f, s2 = 0.f;
    #pragma unroll
    for (int dq = 0; dq < 8; ++dq) {
        float4 xv = *(const float4*)&x[off + dq * 4];
        float r0 = xv.x + o[dq*4+0] * inv;
        float r1 = xv.y + o[dq*4+1] * inv;
        float r2 = xv.z + o[dq*4+2] * inv;
        float r3 = xv.w + o[dq*4+3] * inv;
        *(float4*)&outb[t * OB3 + h * DHn + dq * 4] = make_float4(r0, r1, r2, r3);
        s  += r0 + r1 + r2 + r3;
        s2 += r0*r0 + r1*r1 + r2*r2 + r3*r3;
    }
    #pragma unroll
    for (int msk = 1; msk < 8; msk <<= 1) {
        s += __shfl_xor(s, msk); s2 += __shfl_xor(s2, msk);
    }
    if (h == 0) {
        const float mean = s * (1.f / Cn);
        const float var  = s2 * (1.f / Cn) - mean * mean;
        mS[t] = mean;
        rS[t] = rsqrtf(var + 1e-5f);
    }
    __syncthreads();

    // ---- drain: coalesced stores (wave covers 1KB contiguous per instr) ----
    const int lane = tid & 63;
    const float4 g4 = *(const float4*)&g2[lane * 4];
    const float4 b4 = *(const float4*)&b2[lane * 4];
    const size_t gbase = ((size_t)b * Nn + nbase) * Cn;
    #pragma unroll
    for (int j = 0; j < 8; ++j) {
        const int e   = j * 1024 + tid * 4;
        const int row = e >> 8;             // wave-uniform
        const int c   = e & 255;            // == lane*4
        float4 rv = *(const float4*)&outb[row * OB3 + c];
        *(float4*)&x2[gbase + e] = rv;
        const float mean = mS[row], rr = rS[row];
        ushort4 yb;
        yb.x = f2bf((rv.x - mean) * rr * g4.x + b4.x);
        yb.y = f2bf((rv.y - mean) * rr * g4.y + b4.y);
        yb.z = f2bf((rv.z - mean) * rr * g4.z + b4.z);
        yb.w = f2bf((rv.w - mean) * rr * g4.w + b4.w);
        *(ushort4*)&ybf[gbase + e] = yb;
    }
}

// ---------------------------------------------------------------------------
// Weight cast + transpose: W[R][Cc] f32 -> Wt[Cc][R] bf16
// ---------------------------------------------------------------------------
__global__ void wcast_kernel(const float* __restrict__ W, ushort* __restrict__ Wt, int R, int Cc)
{
    int idx = blockIdx.x * 256 + threadIdx.x;
    if (idx < R * Cc) {
        int r = idx / Cc, c = idx % Cc;
        Wt[(size_t)c * R + r] = f2bf(W[idx]);
    }
}

extern "C" void kernel_launch(void* const* d_in, const int* in_sizes, int n_in,
                              void* d_out, int out_size, void* d_ws, size_t ws_size,
                              hipStream_t stream)
{
    const float* x    = (const float*)d_in[0];
    const float* rot  = (const float*)d_in[1];
    const float* n1g  = (const float*)d_in[2];
    const float* n1b  = (const float*)d_in[3];
    const float* q_w  = (const float*)d_in[4];
    const float* kv_w = (const float*)d_in[5];
    const float* n2g  = (const float*)d_in[6];
    const float* n2b  = (const float*)d_in[7];
    const float* fc1w = (const float*)d_in[8];
    const float* fc1b = (const float*)d_in[9];
    const float* fc2w = (const float*)d_in[10];
    const float* fc2b = (const float*)d_in[11];

    char* ws = (char*)d_ws;
    const size_t XBF_OFF = 0;                  // 67108864  bf16 x_ [131072][256]
    const size_t S_OFF   = 67108864ull;        // 67108864  bf16 attention logits S
    const size_t H_OFF   = 0;                  // 268435456 bf16 h (aliases xbf+S, dead by fc1)
    const size_t X2_OFF  = 268435456ull;       // 134217728 f32 x2  (first 67MB: pool_part/WsT)
    const size_t PP_OFF  = X2_OFF;             // 67108864  f32 pool_part [2048][32][256]
    const size_t CP_OFF  = X2_OFF + 67108864;  // 262144    f32 cnt_part [2048][32]
    const size_t Y_OFF   = 402653184ull;       // 67108864  bf16 y
    const size_t CT_OFF  = 469762048ull;       // 2048      f32 countsF
    const size_t KB_OFF  = CT_OFF + 4096;      // 524288    f32 k [16][8][32][32]
    const size_t VB_OFF  = KB_OFF + 524288;    // 524288    f32 v
    const size_t F1T_OFF = VB_OFF + 524288;    // 524288    bf16 fc1^T
    const size_t F2T_OFF = F1T_OFF + 524288;   // 524288    bf16 fc2^T

    ushort* xbf    = (ushort*)(ws + XBF_OFF);
    ushort* Sbuf   = (ushort*)(ws + S_OFF);
    ushort* hbf    = (ushort*)(ws + H_OFF);
    float*  x2     = (float*)(ws + X2_OFF);
    float*  ppart  = (float*)(ws + PP_OFF);
    float*  cpart  = (float*)(ws + CP_OFF);
    ushort* WsT    = (ushort*)(ws + X2_OFF);   // 2MB, aliases pool_part (dead after kv)
    ushort* ybf    = (ushort*)(ws + Y_OFF);
    float*  countsF= (float*)(ws + CT_OFF);
    float*  kbuf   = (float*)(ws + KB_OFF);
    float*  vbuf   = (float*)(ws + VB_OFF);
    ushort* f1T    = (ushort*)(ws + F1T_OFF);
    ushort* f2T    = (ushort*)(ws + F2T_OFF);

    wcast_kernel<<<dim3(1024), 256, 0, stream>>>(fc1w, f1T, 256, 1024);
    wcast_kernel<<<dim3(1024), 256, 0, stream>>>(fc2w, f2T, 1024, 256);

    ln1_pool_kernel<<<dim3(Bn * 128), 256, 0, stream>>>(x, rot, n1g, n1b, xbf, ppart, cpart);
    kv_kernel<<<dim3(Bn * Mn), 256, 0, stream>>>(ppart, cpart, kv_w, kbuf, vbuf, countsF);
    ws_build_kernel<<<dim3(Bn * Hn), 256, 0, stream>>>(q_w, kbuf, WsT);
    // S = x_hat @ Ws_b : replaces the q projection (same GEMM shape, per-batch B)
    gemm_bt<0><<<dim3(2 * 1024), 256, 0, stream>>>(xbf, WsT, nullptr, nullptr, Sbuf, Bn * Nn, Cn, Cn, Cn * Cn);
    attn3_ln2_kernel<<<dim3(Bn * 256), 256, 0, stream>>>(Sbuf, vbuf, countsF, x, n2g, n2b, x2, ybf);
    gemm_bt<1><<<dim3(8 * 1024), 256, 0, stream>>>(ybf, f1T, fc1b, nullptr, hbf, Bn * Nn, DFFn, Cn, 0);
    gemm_bt<2><<<dim3(2 * 1024), 256, 0, stream>>>(hbf, f2T, fc2b, x2, d_out, Bn * Nn, Cn, DFFn, 0);
}